// Round 6
// baseline (1926.166 us; speedup 1.0000x reference)
//
#include <hip/hip_runtime.h>
#include <hip/hip_bf16.h>

// Problem constants
#define B_   64
#define T_   512
#define EMB_ 256
#define H_   256          // hidden per direction
#define L_   9
#define NROW (B_*T_)      // 32768
#define NG   2048         // both directions' gates
#define SENT 0xFFFFFFFFFFFFFFFFull

typedef __attribute__((ext_vector_type(8))) short bf16x8;
typedef __attribute__((ext_vector_type(4))) float f32x4;

__device__ __forceinline__ float bf2f(unsigned short u) {
    union { unsigned int i; float f; } c; c.i = ((unsigned int)u) << 16; return c.f;
}
__device__ __forceinline__ unsigned int f2bf(float f) {
    union { unsigned int i; float f; } c; c.f = f;
    unsigned int i = c.i;
    return (i + 0x7FFFu + ((i >> 16) & 1u)) >> 16;
}
__device__ __forceinline__ float sigmf(float x) { return 1.0f / (1.0f + __expf(-x)); }
__device__ __forceinline__ float tanh_fast(float x) {
    return 2.0f / (1.0f + __expf(-2.0f * x)) - 1.0f;
}
// Raw block barrier ordering LDS only (no vmcnt drain on the critical path).
__device__ __forceinline__ void bar_lds() {
    asm volatile("s_waitcnt lgkmcnt(0)\n\ts_barrier" ::: "memory");
}

// ---------------------------------------------------------------------------
// bias[n] = b_ih + b_hh (both dirs)
// ---------------------------------------------------------------------------
__global__ void __launch_bounds__(256) bias_k(
    const float* __restrict__ bihf, const float* __restrict__ bhhf,
    const float* __restrict__ bihb, const float* __restrict__ bhhb,
    float* __restrict__ bias)
{
    int i = blockIdx.x * 256 + threadIdx.x;   // 0..2047
    if (i < 1024) bias[i] = bihf[i] + bhhf[i];
    else          bias[i] = bihb[i - 1024] + bhhb[i - 1024];
}

// Pre-fill h_hist with the sentinel pattern (all-ones = NaN bf16).
// Plain 16B stores; visibility to lstm's MALL-scope atomics is guaranteed by
// the inter-dispatch release/acquire on the stream.
__global__ void __launch_bounds__(256) fill_sent(uint4* __restrict__ p)
{
    size_t i = ((size_t)blockIdx.x * 256 + threadIdx.x) * 2;
    uint4 v = make_uint4(~0u, ~0u, ~0u, ~0u);
    p[i] = v;
    p[i + 1] = v;
}

// ---------------------------------------------------------------------------
// xg GEMM: xg[row][n] = sum_k emb[ids[row]][k] * w(n)[k] + bias[n]  (bf16 out)
// ---------------------------------------------------------------------------
#define BM 128
#define BN 128
#define BK 16
__global__ void __launch_bounds__(256) xg_gemm(
    const float* __restrict__ emb, const int* __restrict__ ids,
    const float* __restrict__ w_f, const float* __restrict__ w_b,
    const float* __restrict__ bias, unsigned short* __restrict__ xg)
{
    __shared__ float As[BK][BM];
    __shared__ float Bs[BK][BN];
    __shared__ int rowtok[BM];
    int tid = threadIdx.x;
    int row0 = blockIdx.x * BM;
    int col0 = blockIdx.y * BN;
    if (tid < BM) rowtok[tid] = ids[row0 + tid];
    __syncthreads();

    int tx = tid & 15, ty = tid >> 4;
    float acc[8][8];
#pragma unroll
    for (int i = 0; i < 8; ++i)
#pragma unroll
        for (int j = 0; j < 8; ++j) acc[i][j] = 0.0f;

    for (int k0 = 0; k0 < EMB_; k0 += BK) {
#pragma unroll
        for (int l = 0; l < 2; ++l) {
            int idx = tid + l * 256;
            int r  = idx >> 2;
            int kc = (idx & 3) * 4;
            const float* src = emb + (size_t)rowtok[r] * EMB_ + k0 + kc;
            float4 v = *(const float4*)src;
            As[kc + 0][r] = v.x; As[kc + 1][r] = v.y;
            As[kc + 2][r] = v.z; As[kc + 3][r] = v.w;
        }
#pragma unroll
        for (int l = 0; l < 2; ++l) {
            int idx = tid + l * 256;
            int c  = idx >> 2;
            int kc = (idx & 3) * 4;
            int n  = col0 + c;
            const float* wr = (n < 1024) ? (w_f + (size_t)n * EMB_)
                                         : (w_b + (size_t)(n - 1024) * EMB_);
            float4 v = *(const float4*)(wr + k0 + kc);
            Bs[kc + 0][c] = v.x; Bs[kc + 1][c] = v.y;
            Bs[kc + 2][c] = v.z; Bs[kc + 3][c] = v.w;
        }
        __syncthreads();
#pragma unroll
        for (int k = 0; k < BK; ++k) {
            float a[8], b[8];
            *(float4*)&a[0] = *(float4*)&As[k][ty * 8];
            *(float4*)&a[4] = *(float4*)&As[k][ty * 8 + 4];
            *(float4*)&b[0] = *(float4*)&Bs[k][tx * 8];
            *(float4*)&b[4] = *(float4*)&Bs[k][tx * 8 + 4];
#pragma unroll
            for (int i = 0; i < 8; ++i)
#pragma unroll
                for (int j = 0; j < 8; ++j) acc[i][j] += a[i] * b[j];
        }
        __syncthreads();
    }
#pragma unroll
    for (int i = 0; i < 8; ++i) {
        size_t row = (size_t)row0 + ty * 8 + i;
#pragma unroll
        for (int j4 = 0; j4 < 2; ++j4) {
            int nb = col0 + tx * 8 + j4 * 4;
            ushort4 o;
            o.x = (unsigned short)f2bf(acc[i][j4 * 4 + 0] + bias[nb + 0]);
            o.y = (unsigned short)f2bf(acc[i][j4 * 4 + 1] + bias[nb + 1]);
            o.z = (unsigned short)f2bf(acc[i][j4 * 4 + 2] + bias[nb + 2]);
            o.w = (unsigned short)f2bf(acc[i][j4 * 4 + 3] + bias[nb + 3]);
            *(ushort4*)(xg + row * NG + nb) = o;
        }
    }
}

// ---------------------------------------------------------------------------
// Persistent cluster LSTM, register-resident weights + MFMA, K-split waves,
// SENTINEL DATA POLLING (no flags, no producer drain).
// 32 blocks x 256 threads. cluster = bid & 7 = (dir, 16-batch group);
// 4 blocks per cluster; block blk owns output h-dims [blk*64, blk*64+64).
// Wave kq computes all 4 gates' partials over k in [kq*64, kq*64+64):
//  - kq == blk: reads previous h from an LDS stash (no global trip)
//  - kq != blk: polls its own h_hist data words (relaxed agent atomics)
//    until no lane sees the sentinel; the successful load IS the data.
// h_hist pre-filled with sentinel; every word written exactly once per run.
// ---------------------------------------------------------------------------
__global__ void __launch_bounds__(256, 1) lstm_mfma(
    const unsigned short* __restrict__ xg,
    const float* __restrict__ w_hh_f, const float* __restrict__ w_hh_b,
    unsigned long long* __restrict__ h_hist)  // [2][64][512][64] ull (4 bf16 each)
{
    const int bid = blockIdx.x;      // 0..31
    const int cluster = bid & 7;
    const int blk = bid >> 3;        // 0..3  (output h-slice owner)
    const int dir = cluster >> 2;
    const int bbase = (cluster & 3) * 16;
    const int j0 = blk * 64;
    const int tid = threadIdx.x;
    const int kq = tid >> 6;         // wave's K-slice == producer block id
    const int l = tid & 63;
    const int l15 = l & 15, lq = l >> 4;

    const float* whh = dir ? w_hh_b : w_hh_f;

    // Stationary B fragments:
    // bfrag[g][nt][kt][e] = w[(g*256 + j0 + nt*16 + l15)][kq*64 + kt*32 + lq*8 + e]
    bf16x8 bfrag[4][4][2];
#pragma unroll
    for (int g = 0; g < 4; ++g)
#pragma unroll
        for (int nt = 0; nt < 4; ++nt) {
            const float* wr = whh + (size_t)(g * 256 + j0 + nt * 16 + l15) * 256
                                  + kq * 64 + lq * 8;
#pragma unroll
            for (int kt = 0; kt < 2; ++kt) {
                bf16x8 f;
#pragma unroll
                for (int e = 0; e < 8; ++e)
                    f[e] = (short)f2bf(wr[kt * 32 + e]);
                bfrag[g][nt][kt] = f;
            }
        }

    __shared__ float pg[4][4][16][68];      // [kq][gate][b][j-local]
    __shared__ unsigned short h_self[16][72]; // own block's h slice (bf16)

    // cell-update ownership: b = bbase + ub, j = j0 + jj0 + q
    const int ub = tid >> 4, jj0 = (tid & 15) * 4;
    float cst[4] = {0.f, 0.f, 0.f, 0.f};

    const size_t hrow_rd = (size_t)(dir * 64 + bbase + l15) * 512;
    const size_t hrow_wr = (size_t)(dir * 64 + bbase + ub) * 512;
    const unsigned short* xbase = xg + (size_t)(bbase + ub) * T_ * NG + dir * 1024 + j0 + jj0;

    for (int s = 0; s < T_; ++s) {
        const int t = dir ? (T_ - 1 - s) : s;

        // xg loads: issued before any waiting, consumed at combine.
        ushort4 xq[4];
#pragma unroll
        for (int g = 0; g < 4; ++g)
            xq[g] = *(const ushort4*)(xbase + (size_t)t * NG + g * 256);

        f32x4 acc[4][4];
#pragma unroll
        for (int g = 0; g < 4; ++g)
#pragma unroll
            for (int nt = 0; nt < 4; ++nt)
                acc[g][nt] = (f32x4){0.f, 0.f, 0.f, 0.f};

        if (s > 0) {
            bf16x8 af[2];
            if (kq == blk) {
                // self slice from LDS (written last step, ordered by bar_lds)
                af[0] = *(const bf16x8*)&h_self[l15][lq * 8];
                af[1] = *(const bf16x8*)&h_self[l15][32 + lq * 8];
            } else {
                const int tp = dir ? (t + 1) : (t - 1);
                const unsigned long long* hb =
                    h_hist + (hrow_rd + tp) * 64 + kq * 16 + lq * 2;
                union UA { unsigned long long u[2]; bf16x8 v; } a0, a1;
                do {
                    a0.u[0] = __hip_atomic_load(hb + 0, __ATOMIC_RELAXED, __HIP_MEMORY_SCOPE_AGENT);
                    a0.u[1] = __hip_atomic_load(hb + 1, __ATOMIC_RELAXED, __HIP_MEMORY_SCOPE_AGENT);
                    a1.u[0] = __hip_atomic_load(hb + 8, __ATOMIC_RELAXED, __HIP_MEMORY_SCOPE_AGENT);
                    a1.u[1] = __hip_atomic_load(hb + 9, __ATOMIC_RELAXED, __HIP_MEMORY_SCOPE_AGENT);
                } while (__any((a0.u[0] == SENT) || (a0.u[1] == SENT) ||
                               (a1.u[0] == SENT) || (a1.u[1] == SENT)));
                af[0] = a0.v; af[1] = a1.v;
            }
#pragma unroll
            for (int g = 0; g < 4; ++g)
#pragma unroll
                for (int nt = 0; nt < 4; ++nt)
#pragma unroll
                    for (int kt = 0; kt < 2; ++kt)
                        acc[g][nt] = __builtin_amdgcn_mfma_f32_16x16x32_bf16(
                            af[kt], bfrag[g][nt][kt], acc[g][nt], 0, 0, 0);
        }

        // partial gates -> LDS: pg[kq][g][b = lq*4+r][nt*16 + l15]
#pragma unroll
        for (int g = 0; g < 4; ++g)
#pragma unroll
            for (int nt = 0; nt < 4; ++nt)
#pragma unroll
                for (int r = 0; r < 4; ++r)
                    pg[kq][g][lq * 4 + r][nt * 16 + l15] = acc[g][nt][r];
        bar_lds();

        // combine partials + xg, cell update (4 h-values per thread)
        union F4 { float4 v; float a[4]; };
        F4 gv[4];
#pragma unroll
        for (int g = 0; g < 4; ++g) {
            float4 v = make_float4(bf2f(xq[g].x), bf2f(xq[g].y),
                                   bf2f(xq[g].z), bf2f(xq[g].w));
#pragma unroll
            for (int q2 = 0; q2 < 4; ++q2) {
                const float4 p = *(const float4*)&pg[q2][g][ub][jj0];
                v.x += p.x; v.y += p.y; v.z += p.z; v.w += p.w;
            }
            gv[g].v = v;
        }
        float hv[4];
#pragma unroll
        for (int q = 0; q < 4; ++q) {
            float ci = sigmf(gv[1].a[q]) * cst[q] + sigmf(gv[0].a[q]) * tanh_fast(gv[2].a[q]);
            cst[q] = ci;
            hv[q] = sigmf(gv[3].a[q]) * tanh_fast(ci);
        }

        // pack 4 bf16; publish to MALL (consumers poll this word) + LDS stash
        unsigned int lo = f2bf(hv[0]) | (f2bf(hv[1]) << 16);
        unsigned int hi = f2bf(hv[2]) | (f2bf(hv[3]) << 16);
        unsigned long long pw = (unsigned long long)lo | ((unsigned long long)hi << 32);
        __hip_atomic_store(&h_hist[(hrow_wr + t) * 64 + ((j0 + jj0) >> 2)], pw,
                           __ATOMIC_RELAXED, __HIP_MEMORY_SCOPE_AGENT);
        ushort4 hs;
        hs.x = (unsigned short)(lo & 0xFFFF); hs.y = (unsigned short)(lo >> 16);
        hs.z = (unsigned short)(hi & 0xFFFF); hs.w = (unsigned short)(hi >> 16);
        *(ushort4*)&h_self[ub][jj0] = hs;
        bar_lds();
    }
}

// ---------------------------------------------------------------------------
// Emissions (reads bf16 h history)
// ---------------------------------------------------------------------------
__global__ void __launch_bounds__(256) emis_k(
    const unsigned short* __restrict__ h_hist, const float* __restrict__ w_cls,
    const float* __restrict__ b_cls, float* __restrict__ em)
{
    int wid = threadIdx.x >> 6, lane = threadIdx.x & 63;
    size_t row = (size_t)blockIdx.x * 4 + wid;       // b*T + t
    const unsigned short* hf = h_hist + row * 256;
    const unsigned short* hb = h_hist + (size_t)64 * 512 * 256 + row * 256;
    ushort4 u0 = *(const ushort4*)(hf + 4 * lane);
    ushort4 u1 = *(const ushort4*)(hb + 4 * lane);
    float a0x = bf2f(u0.x), a0y = bf2f(u0.y), a0z = bf2f(u0.z), a0w = bf2f(u0.w);
    float a1x = bf2f(u1.x), a1y = bf2f(u1.y), a1z = bf2f(u1.z), a1w = bf2f(u1.w);
#pragma unroll
    for (int l = 0; l < L_; ++l) {
        const float* wr = w_cls + (size_t)l * 512;
        float4 w0 = *(const float4*)(wr + 4 * lane);
        float4 w1 = *(const float4*)(wr + 256 + 4 * lane);
        float d = a0x * w0.x + a0y * w0.y + a0z * w0.z + a0w * w0.w
                + a1x * w1.x + a1y * w1.y + a1z * w1.z + a1w * w1.w;
#pragma unroll
        for (int off = 32; off; off >>= 1) d += __shfl_down(d, off);
        if (lane == 0) em[row * L_ + l] = d + b_cls[l];
    }
}

// ---------------------------------------------------------------------------
// CRF NLL
// ---------------------------------------------------------------------------
__global__ void __launch_bounds__(64) crf_k(
    const float* __restrict__ em, const int* __restrict__ labels,
    const int* __restrict__ mask, const float* __restrict__ trans,
    const float* __restrict__ startv, const float* __restrict__ endv,
    float* __restrict__ out)
{
    int b = blockIdx.x, lane = threadIdx.x;
    const float* emb_ = em + (size_t)b * T_ * L_;
    const int* lab = labels + (size_t)b * T_;
    const int* msk = mask + (size_t)b * T_;
    __shared__ float alpha[L_];
    __shared__ float trs[81];
    for (int i = lane; i < 81; i += 64) trs[i] = trans[i];
    __syncthreads();

    float np = 0.0f;
    for (int t = 1 + lane; t < T_; t += 64)
        if (msk[t]) np += trs[lab[t - 1] * L_ + lab[t]] + emb_[(size_t)t * L_ + lab[t]];
    int mc = 0;
    for (int t = lane; t < T_; t += 64) mc += (msk[t] != 0);
#pragma unroll
    for (int off = 32; off; off >>= 1) {
        np += __shfl_down(np, off);
        mc += __shfl_down(mc, off);
    }
    float num = 0.0f;
    if (lane == 0) {
        int last = mc - 1;
        num = np + startv[lab[0]] + emb_[lab[0]] + endv[lab[last]];
    }

    if (lane < L_) alpha[lane] = startv[lane] + emb_[lane];
    __syncthreads();
    for (int t = 1; t < T_; ++t) {
        float na = 0.0f;
        if (lane < L_) {
            float m = -1e30f;
#pragma unroll
            for (int i = 0; i < L_; ++i) m = fmaxf(m, alpha[i] + trs[i * L_ + lane]);
            float s = 0.0f;
#pragma unroll
            for (int i = 0; i < L_; ++i) s += __expf(alpha[i] + trs[i * L_ + lane] - m);
            na = m + __logf(s) + emb_[(size_t)t * L_ + lane];
            if (!msk[t]) na = alpha[lane];
        }
        __syncthreads();
        if (lane < L_) alpha[lane] = na;
        __syncthreads();
    }
    float v = (lane < L_) ? alpha[lane] + endv[lane] : -1e30f;
    float m = v;
#pragma unroll
    for (int off = 32; off; off >>= 1) m = fmaxf(m, __shfl_xor(m, off));
    float s = (lane < L_) ? __expf(v - m) : 0.0f;
#pragma unroll
    for (int off = 32; off; off >>= 1) s += __shfl_xor(s, off);
    if (lane == 0) {
        float logZ = m + __logf(s);
        atomicAdd(out, (logZ - num) / (float)B_);
    }
}

__global__ void zero_out_k(float* out) { out[0] = 0.0f; }
__global__ void ws_fail_k(float* out, float v) { out[0] = v; }

// ---------------------------------------------------------------------------
extern "C" void kernel_launch(void* const* d_in, const int* in_sizes, int n_in,
                              void* d_out, int out_size, void* d_ws, size_t ws_size,
                              hipStream_t stream)
{
    const int*   ids    = (const int*)  d_in[0];
    const int*   amask  = (const int*)  d_in[1];
    const int*   labels = (const int*)  d_in[2];
    const float* emb    = (const float*)d_in[3];
    const float* w_ih_f = (const float*)d_in[4];
    const float* w_hh_f = (const float*)d_in[5];
    const float* b_ih_f = (const float*)d_in[6];
    const float* b_hh_f = (const float*)d_in[7];
    const float* w_ih_b = (const float*)d_in[8];
    const float* w_hh_b = (const float*)d_in[9];
    const float* b_ih_b = (const float*)d_in[10];
    const float* b_hh_b = (const float*)d_in[11];
    const float* w_cls  = (const float*)d_in[12];
    const float* b_cls  = (const float*)d_in[13];
    const float* trans  = (const float*)d_in[14];
    const float* startv = (const float*)d_in[15];
    const float* endv   = (const float*)d_in[16];
    float* out = (float*)d_out;

    // workspace layout
    size_t o_xg    = 0;                                    // bf16 xg: 128 MB
    size_t o_bias  = o_xg + (size_t)NROW * NG * 2;
    size_t o_hh    = o_bias + 2048 * 4;                    // h_hist: 33.5 MB
    size_t o_em    = o_hh + (size_t)2 * B_ * T_ * 64 * 8;
    size_t total   = o_em + (size_t)NROW * L_ * 4;

    if (ws_size < total) {
        ws_fail_k<<<1, 1, 0, stream>>>(out, -1.0e8f - (float)(ws_size >> 20));
        return;
    }

    unsigned short* xg         = (unsigned short*)((char*)d_ws + o_xg);
    float* bias                = (float*)((char*)d_ws + o_bias);
    unsigned long long* h_hist = (unsigned long long*)((char*)d_ws + o_hh);
    float* em                  = (float*)((char*)d_ws + o_em);

    bias_k<<<8, 256, 0, stream>>>(b_ih_f, b_hh_f, b_ih_b, b_hh_b, bias);
    fill_sent<<<4096, 256, 0, stream>>>((uint4*)h_hist);
    xg_gemm<<<dim3(NROW / BM, NG / BN), 256, 0, stream>>>(emb, ids, w_ih_f, w_ih_b, bias, xg);
    lstm_mfma<<<32, 256, 0, stream>>>(xg, w_hh_f, w_hh_b, h_hist);
    emis_k<<<NROW / 4, 256, 0, stream>>>((const unsigned short*)h_hist, w_cls, b_cls, em);
    zero_out_k<<<1, 1, 0, stream>>>(out);
    crf_k<<<B_, 64, 0, stream>>>(em, labels, amask, trans, startv, endv, out);
}

// Round 7
// 1848.331 us; speedup vs baseline: 1.0421x; 1.0421x over previous
//
#include <hip/hip_runtime.h>
#include <hip/hip_bf16.h>

// Problem constants
#define B_   64
#define T_   512
#define EMB_ 256
#define H_   256          // hidden per direction
#define L_   9
#define NROW (B_*T_)      // 32768
#define NG   2048         // both directions' gates

typedef __attribute__((ext_vector_type(4))) float f32x4;

__device__ __forceinline__ float bf2f(unsigned short u) {
    union { unsigned int i; float f; } c; c.i = ((unsigned int)u) << 16; return c.f;
}
__device__ __forceinline__ unsigned int f2bf(float f) {
    union { unsigned int i; float f; } c; c.f = f;
    unsigned int i = c.i;
    return (i + 0x7FFFu + ((i >> 16) & 1u)) >> 16;
}
__device__ __forceinline__ float sigmf(float x) {
    return __builtin_amdgcn_rcpf(1.0f + __expf(-x));
}
__device__ __forceinline__ float tanh_fast(float x) {
    return 2.0f * __builtin_amdgcn_rcpf(1.0f + __expf(-2.0f * x)) - 1.0f;
}
// Raw block barrier ordering LDS only.
__device__ __forceinline__ void bar_lds() {
    asm volatile("s_waitcnt lgkmcnt(0)\n\ts_barrier" ::: "memory");
}

// ---------------------------------------------------------------------------
// bias[n] = b_ih + b_hh (both dirs)
// ---------------------------------------------------------------------------
__global__ void __launch_bounds__(256) bias_k(
    const float* __restrict__ bihf, const float* __restrict__ bhhf,
    const float* __restrict__ bihb, const float* __restrict__ bhhb,
    float* __restrict__ bias)
{
    int i = blockIdx.x * 256 + threadIdx.x;   // 0..2047
    if (i < 1024) bias[i] = bihf[i] + bhhf[i];
    else          bias[i] = bihb[i - 1024] + bhhb[i - 1024];
}

// ---------------------------------------------------------------------------
// Convert w_hh (both dirs) to fp8 e4m3, same row-major [1024][256] layout.
// ---------------------------------------------------------------------------
__global__ void __launch_bounds__(256) prep_w8(
    const float* __restrict__ wf, const float* __restrict__ wb,
    unsigned int* __restrict__ w8)
{
    int i = blockIdx.x * 256 + threadIdx.x;   // word index, 131072 total
    const float* src = (i < 65536) ? wf : wb;
    int j = (i & 65535) * 4;
    unsigned int pk = __builtin_amdgcn_cvt_pk_fp8_f32(src[j], src[j + 1], 0, false);
    pk = __builtin_amdgcn_cvt_pk_fp8_f32(src[j + 2], src[j + 3], pk, true);
    w8[i] = pk;
}

// ---------------------------------------------------------------------------
// xg GEMM: xg[row][n] = sum_k emb[ids[row]][k] * w(n)[k] + bias[n]  (bf16 out)
// ---------------------------------------------------------------------------
#define BM 128
#define BN 128
#define BK 16
__global__ void __launch_bounds__(256) xg_gemm(
    const float* __restrict__ emb, const int* __restrict__ ids,
    const float* __restrict__ w_f, const float* __restrict__ w_b,
    const float* __restrict__ bias, unsigned short* __restrict__ xg)
{
    __shared__ float As[BK][BM];
    __shared__ float Bs[BK][BN];
    __shared__ int rowtok[BM];
    int tid = threadIdx.x;
    int row0 = blockIdx.x * BM;
    int col0 = blockIdx.y * BN;
    if (tid < BM) rowtok[tid] = ids[row0 + tid];
    __syncthreads();

    int tx = tid & 15, ty = tid >> 4;
    float acc[8][8];
#pragma unroll
    for (int i = 0; i < 8; ++i)
#pragma unroll
        for (int j = 0; j < 8; ++j) acc[i][j] = 0.0f;

    for (int k0 = 0; k0 < EMB_; k0 += BK) {
#pragma unroll
        for (int l = 0; l < 2; ++l) {
            int idx = tid + l * 256;
            int r  = idx >> 2;
            int kc = (idx & 3) * 4;
            const float* src = emb + (size_t)rowtok[r] * EMB_ + k0 + kc;
            float4 v = *(const float4*)src;
            As[kc + 0][r] = v.x; As[kc + 1][r] = v.y;
            As[kc + 2][r] = v.z; As[kc + 3][r] = v.w;
        }
#pragma unroll
        for (int l = 0; l < 2; ++l) {
            int idx = tid + l * 256;
            int c  = idx >> 2;
            int kc = (idx & 3) * 4;
            int n  = col0 + c;
            const float* wr = (n < 1024) ? (w_f + (size_t)n * EMB_)
                                         : (w_b + (size_t)(n - 1024) * EMB_);
            float4 v = *(const float4*)(wr + k0 + kc);
            Bs[kc + 0][c] = v.x; Bs[kc + 1][c] = v.y;
            Bs[kc + 2][c] = v.z; Bs[kc + 3][c] = v.w;
        }
        __syncthreads();
#pragma unroll
        for (int k = 0; k < BK; ++k) {
            float a[8], b[8];
            *(float4*)&a[0] = *(float4*)&As[k][ty * 8];
            *(float4*)&a[4] = *(float4*)&As[k][ty * 8 + 4];
            *(float4*)&b[0] = *(float4*)&Bs[k][tx * 8];
            *(float4*)&b[4] = *(float4*)&Bs[k][tx * 8 + 4];
#pragma unroll
            for (int i = 0; i < 8; ++i)
#pragma unroll
                for (int j = 0; j < 8; ++j) acc[i][j] += a[i] * b[j];
        }
        __syncthreads();
    }
#pragma unroll
    for (int i = 0; i < 8; ++i) {
        size_t row = (size_t)row0 + ty * 8 + i;
#pragma unroll
        for (int j4 = 0; j4 < 2; ++j4) {
            int nb = col0 + tx * 8 + j4 * 4;
            ushort4 o;
            o.x = (unsigned short)f2bf(acc[i][j4 * 4 + 0] + bias[nb + 0]);
            o.y = (unsigned short)f2bf(acc[i][j4 * 4 + 1] + bias[nb + 1]);
            o.z = (unsigned short)f2bf(acc[i][j4 * 4 + 2] + bias[nb + 2]);
            o.w = (unsigned short)f2bf(acc[i][j4 * 4 + 3] + bias[nb + 3]);
            *(ushort4*)(xg + row * NG + nb) = o;
        }
    }
}

// ---------------------------------------------------------------------------
// Fused single-block LSTM: one block per (dir, 16-batch group). 512 threads.
// Full 1024x256 gate matrix in fp8 e4m3 register fragments (128 VGPR/thread).
// Wave w owns j in [w*32, w*32+32) for ALL 4 gates -> cell update is fully
// lane-local (C/D layout puts gates i,f,g,o for a given (b,j) in one lane).
// h kept as fp8 in a 4 KB LDS buffer; no cross-block traffic at all.
// ---------------------------------------------------------------------------
__global__ void __launch_bounds__(512) lstm_fused(
    const unsigned short* __restrict__ xg,
    const unsigned long long* __restrict__ w8,   // fp8 [2][1024][256] as u64
    unsigned short* __restrict__ h_hist)         // bf16 [2*64][512][256]
{
    const int bid = blockIdx.x;          // 0..7
    const int dir = bid >> 2;
    const int bbase = (bid & 3) * 16;
    const int tid = threadIdx.x;
    const int w = tid >> 6;              // wave 0..7: j-slice [w*32, w*32+32)
    const int l = tid & 63;
    const int l15 = l & 15, lq = l >> 4;

    __shared__ unsigned long long hbuf[16 * 33];   // fp8 h, row stride 33 u64

    for (int i = tid; i < 16 * 33; i += 512) hbuf[i] = 0ull;

    // Stationary fp8 B fragments: bfrag[g][nt][kt] covers
    // rows n = g*256 + w*32 + nt*16 + l15, k = kt*32 + lq*8 .. +8
    unsigned long long bfrag[4][2][8];
    const unsigned long long* wbp = w8 + (size_t)dir * 32768;
#pragma unroll
    for (int g = 0; g < 4; ++g)
#pragma unroll
        for (int nt = 0; nt < 2; ++nt) {
            int row = g * 256 + w * 32 + nt * 16 + l15;
#pragma unroll
            for (int kt = 0; kt < 8; ++kt)
                bfrag[g][nt][kt] = wbp[row * 32 + kt * 4 + lq];
        }

    float cst[2][4] = {{0.f, 0.f, 0.f, 0.f}, {0.f, 0.f, 0.f, 0.f}};

    // xg prefetch registers: xqr[g][nt][r] for batch b = bbase + lq*4 + r
    unsigned short xqr[4][2][4];
    {
        int t0 = dir ? (T_ - 1) : 0;
#pragma unroll
        for (int r = 0; r < 4; ++r) {
            const unsigned short* xp = xg
                + ((size_t)(bbase + lq * 4 + r) * T_ + t0) * NG
                + dir * 1024 + w * 32 + l15;
#pragma unroll
            for (int g = 0; g < 4; ++g)
#pragma unroll
                for (int nt = 0; nt < 2; ++nt)
                    xqr[g][nt][r] = xp[g * 256 + nt * 16];
        }
    }
    __syncthreads();   // hbuf zeros visible

    for (int s = 0; s < T_; ++s) {
        const int t = dir ? (T_ - 1 - s) : s;

        // 1. acc init from xg (consumes xqr)
        f32x4 acc[4][2];
#pragma unroll
        for (int g = 0; g < 4; ++g)
#pragma unroll
            for (int nt = 0; nt < 2; ++nt)
#pragma unroll
                for (int r = 0; r < 4; ++r)
                    acc[g][nt][r] = bf2f(xqr[g][nt][r]);

        // 2. prefetch next step's xg
        {
            int sn = (s + 1 < T_) ? (s + 1) : s;
            int tn = dir ? (T_ - 1 - sn) : sn;
#pragma unroll
            for (int r = 0; r < 4; ++r) {
                const unsigned short* xp = xg
                    + ((size_t)(bbase + lq * 4 + r) * T_ + tn) * NG
                    + dir * 1024 + w * 32 + l15;
#pragma unroll
                for (int g = 0; g < 4; ++g)
#pragma unroll
                    for (int nt = 0; nt < 2; ++nt)
                        xqr[g][nt][r] = xp[g * 256 + nt * 16];
            }
        }

        // 3. A fragments: h(s-1) fp8 from LDS, m = l15 (batch), k = kt*32+lq*8
        unsigned long long af[8];
#pragma unroll
        for (int kt = 0; kt < 8; ++kt)
            af[kt] = hbuf[l15 * 33 + kt * 4 + lq];

        bar_lds();   // all reads of hbuf done before this step's writes

        // 4. MFMA: 64 per wave
#pragma unroll
        for (int g = 0; g < 4; ++g)
#pragma unroll
            for (int nt = 0; nt < 2; ++nt)
#pragma unroll
                for (int kt = 0; kt < 8; ++kt)
                    acc[g][nt] = __builtin_amdgcn_mfma_f32_16x16x32_fp8_fp8(
                        (long long)af[kt], (long long)bfrag[g][nt][kt],
                        acc[g][nt], 0, 0, 0);

        // 5. lane-local cell update + stores (b = lq*4+r, j = w*32+nt*16+l15)
        unsigned char* hb8 = (unsigned char*)hbuf;
#pragma unroll
        for (int nt = 0; nt < 2; ++nt)
#pragma unroll
            for (int r = 0; r < 4; ++r) {
                float gi = acc[0][nt][r], gf = acc[1][nt][r];
                float gg = acc[2][nt][r], go = acc[3][nt][r];
                float c = sigmf(gf) * cst[nt][r] + sigmf(gi) * tanh_fast(gg);
                cst[nt][r] = c;
                float h = sigmf(go) * tanh_fast(c);
                int b = lq * 4 + r;
                int j = w * 32 + nt * 16 + l15;
                h_hist[((size_t)(dir * 64 + bbase + b) * T_ + t) * 256 + j] =
                    (unsigned short)f2bf(h);
                unsigned int p8 = __builtin_amdgcn_cvt_pk_fp8_f32(h, h, 0, false);
                hb8[b * 264 + j] = (unsigned char)(p8 & 0xffu);
            }
        bar_lds();   // writes visible before next step's reads
    }
}

// ---------------------------------------------------------------------------
// Emissions (reads bf16 h history)
// ---------------------------------------------------------------------------
__global__ void __launch_bounds__(256) emis_k(
    const unsigned short* __restrict__ h_hist, const float* __restrict__ w_cls,
    const float* __restrict__ b_cls, float* __restrict__ em)
{
    int wid = threadIdx.x >> 6, lane = threadIdx.x & 63;
    size_t row = (size_t)blockIdx.x * 4 + wid;       // b*T + t
    const unsigned short* hf = h_hist + row * 256;
    const unsigned short* hb = h_hist + (size_t)64 * 512 * 256 + row * 256;
    ushort4 u0 = *(const ushort4*)(hf + 4 * lane);
    ushort4 u1 = *(const ushort4*)(hb + 4 * lane);
    float a0x = bf2f(u0.x), a0y = bf2f(u0.y), a0z = bf2f(u0.z), a0w = bf2f(u0.w);
    float a1x = bf2f(u1.x), a1y = bf2f(u1.y), a1z = bf2f(u1.z), a1w = bf2f(u1.w);
#pragma unroll
    for (int l = 0; l < L_; ++l) {
        const float* wr = w_cls + (size_t)l * 512;
        float4 w0 = *(const float4*)(wr + 4 * lane);
        float4 w1 = *(const float4*)(wr + 256 + 4 * lane);
        float d = a0x * w0.x + a0y * w0.y + a0z * w0.z + a0w * w0.w
                + a1x * w1.x + a1y * w1.y + a1z * w1.z + a1w * w1.w;
#pragma unroll
        for (int off = 32; off; off >>= 1) d += __shfl_down(d, off);
        if (lane == 0) em[row * L_ + l] = d + b_cls[l];
    }
}

// ---------------------------------------------------------------------------
// CRF NLL
// ---------------------------------------------------------------------------
__global__ void __launch_bounds__(64) crf_k(
    const float* __restrict__ em, const int* __restrict__ labels,
    const int* __restrict__ mask, const float* __restrict__ trans,
    const float* __restrict__ startv, const float* __restrict__ endv,
    float* __restrict__ out)
{
    int b = blockIdx.x, lane = threadIdx.x;
    const float* emb_ = em + (size_t)b * T_ * L_;
    const int* lab = labels + (size_t)b * T_;
    const int* msk = mask + (size_t)b * T_;
    __shared__ float alpha[L_];
    __shared__ float trs[81];
    for (int i = lane; i < 81; i += 64) trs[i] = trans[i];
    __syncthreads();

    float np = 0.0f;
    for (int t = 1 + lane; t < T_; t += 64)
        if (msk[t]) np += trs[lab[t - 1] * L_ + lab[t]] + emb_[(size_t)t * L_ + lab[t]];
    int mc = 0;
    for (int t = lane; t < T_; t += 64) mc += (msk[t] != 0);
#pragma unroll
    for (int off = 32; off; off >>= 1) {
        np += __shfl_down(np, off);
        mc += __shfl_down(mc, off);
    }
    float num = 0.0f;
    if (lane == 0) {
        int last = mc - 1;
        num = np + startv[lab[0]] + emb_[lab[0]] + endv[lab[last]];
    }

    if (lane < L_) alpha[lane] = startv[lane] + emb_[lane];
    __syncthreads();
    for (int t = 1; t < T_; ++t) {
        float na = 0.0f;
        if (lane < L_) {
            float m = -1e30f;
#pragma unroll
            for (int i = 0; i < L_; ++i) m = fmaxf(m, alpha[i] + trs[i * L_ + lane]);
            float s = 0.0f;
#pragma unroll
            for (int i = 0; i < L_; ++i) s += __expf(alpha[i] + trs[i * L_ + lane] - m);
            na = m + __logf(s) + emb_[(size_t)t * L_ + lane];
            if (!msk[t]) na = alpha[lane];
        }
        __syncthreads();
        if (lane < L_) alpha[lane] = na;
        __syncthreads();
    }
    float v = (lane < L_) ? alpha[lane] + endv[lane] : -1e30f;
    float m = v;
#pragma unroll
    for (int off = 32; off; off >>= 1) m = fmaxf(m, __shfl_xor(m, off));
    float s = (lane < L_) ? __expf(v - m) : 0.0f;
#pragma unroll
    for (int off = 32; off; off >>= 1) s += __shfl_xor(s, off);
    if (lane == 0) {
        float logZ = m + __logf(s);
        atomicAdd(out, (logZ - num) / (float)B_);
    }
}

__global__ void zero_out_k(float* out) { out[0] = 0.0f; }
__global__ void ws_fail_k(float* out, float v) { out[0] = v; }

// ---------------------------------------------------------------------------
extern "C" void kernel_launch(void* const* d_in, const int* in_sizes, int n_in,
                              void* d_out, int out_size, void* d_ws, size_t ws_size,
                              hipStream_t stream)
{
    const int*   ids    = (const int*)  d_in[0];
    const int*   amask  = (const int*)  d_in[1];
    const int*   labels = (const int*)  d_in[2];
    const float* emb    = (const float*)d_in[3];
    const float* w_ih_f = (const float*)d_in[4];
    const float* w_hh_f = (const float*)d_in[5];
    const float* b_ih_f = (const float*)d_in[6];
    const float* b_hh_f = (const float*)d_in[7];
    const float* w_ih_b = (const float*)d_in[8];
    const float* w_hh_b = (const float*)d_in[9];
    const float* b_ih_b = (const float*)d_in[10];
    const float* b_hh_b = (const float*)d_in[11];
    const float* w_cls  = (const float*)d_in[12];
    const float* b_cls  = (const float*)d_in[13];
    const float* trans  = (const float*)d_in[14];
    const float* startv = (const float*)d_in[15];
    const float* endv   = (const float*)d_in[16];
    float* out = (float*)d_out;

    // workspace layout
    size_t o_xg   = 0;                                   // bf16 xg: 128 MB
    size_t o_bias = o_xg + (size_t)NROW * NG * 2;
    size_t o_w8   = o_bias + 2048 * 4;                   // fp8 weights: 512 KB
    size_t o_hh   = o_w8 + (size_t)2 * 1024 * 256;       // h_hist: 32 MB
    size_t o_em   = o_hh + (size_t)2 * B_ * T_ * H_ * 2;
    size_t total  = o_em + (size_t)NROW * L_ * 4;

    if (ws_size < total) {
        ws_fail_k<<<1, 1, 0, stream>>>(out, -1.0e8f - (float)(ws_size >> 20));
        return;
    }

    unsigned short* xg       = (unsigned short*)((char*)d_ws + o_xg);
    float* bias              = (float*)((char*)d_ws + o_bias);
    unsigned int* w8         = (unsigned int*)((char*)d_ws + o_w8);
    unsigned short* h_hist   = (unsigned short*)((char*)d_ws + o_hh);
    float* em                = (float*)((char*)d_ws + o_em);

    bias_k<<<8, 256, 0, stream>>>(b_ih_f, b_hh_f, b_ih_b, b_hh_b, bias);
    prep_w8<<<512, 256, 0, stream>>>(w_hh_f, w_hh_b, w8);
    xg_gemm<<<dim3(NROW / BM, NG / BN), 256, 0, stream>>>(emb, ids, w_ih_f, w_ih_b, bias, xg);
    lstm_fused<<<8, 512, 0, stream>>>(xg, (const unsigned long long*)w8, h_hist);
    emis_k<<<NROW / 4, 256, 0, stream>>>(h_hist, w_cls, b_cls, em);
    zero_out_k<<<1, 1, 0, stream>>>(out);
    crf_k<<<B_, 64, 0, stream>>>(em, labels, amask, trans, startv, endv, out);
}

// Round 8
// 1277.361 us; speedup vs baseline: 1.5079x; 1.4470x over previous
//
#include <hip/hip_runtime.h>
#include <hip/hip_bf16.h>

// Problem constants
#define B_   64
#define T_   512
#define EMB_ 256
#define H_   256          // hidden per direction
#define L_   9
#define NROW (B_*T_)      // 32768
#define NG   2048         // both directions' gates

typedef __attribute__((ext_vector_type(4))) float f32x4;

__device__ __forceinline__ float bf2f(unsigned short u) {
    union { unsigned int i; float f; } c; c.i = ((unsigned int)u) << 16; return c.f;
}
__device__ __forceinline__ unsigned int f2bf(float f) {
    union { unsigned int i; float f; } c; c.f = f;
    unsigned int i = c.i;
    return (i + 0x7FFFu + ((i >> 16) & 1u)) >> 16;
}
__device__ __forceinline__ float sigmf(float x) {
    return __builtin_amdgcn_rcpf(1.0f + __expf(-x));
}
__device__ __forceinline__ float tanh_fast(float x) {
    return 2.0f * __builtin_amdgcn_rcpf(1.0f + __expf(-2.0f * x)) - 1.0f;
}
// Raw block barrier ordering LDS only.
__device__ __forceinline__ void bar_lds() {
    asm volatile("s_waitcnt lgkmcnt(0)\n\ts_barrier" ::: "memory");
}

// ---------------------------------------------------------------------------
// bias[n] = b_ih + b_hh (both dirs)
// ---------------------------------------------------------------------------
__global__ void __launch_bounds__(256) bias_k(
    const float* __restrict__ bihf, const float* __restrict__ bhhf,
    const float* __restrict__ bihb, const float* __restrict__ bhhb,
    float* __restrict__ bias)
{
    int i = blockIdx.x * 256 + threadIdx.x;   // 0..2047
    if (i < 1024) bias[i] = bihf[i] + bhhf[i];
    else          bias[i] = bihb[i - 1024] + bhhb[i - 1024];
}

// ---------------------------------------------------------------------------
// Convert w_hh (both dirs) to fp8 e4m3, same row-major [1024][256] layout.
// ---------------------------------------------------------------------------
__global__ void __launch_bounds__(256) prep_w8(
    const float* __restrict__ wf, const float* __restrict__ wb,
    unsigned int* __restrict__ w8)
{
    int i = blockIdx.x * 256 + threadIdx.x;   // word index, 131072 total
    const float* src = (i < 65536) ? wf : wb;
    int j = (i & 65535) * 4;
    unsigned int pk = __builtin_amdgcn_cvt_pk_fp8_f32(src[j], src[j + 1], 0, false);
    pk = __builtin_amdgcn_cvt_pk_fp8_f32(src[j + 2], src[j + 3], pk, true);
    w8[i] = pk;
}

// ---------------------------------------------------------------------------
// xg GEMM: xg[row][n] = sum_k emb[ids[row]][k] * w(n)[k] + bias[n]  (bf16 out)
// ---------------------------------------------------------------------------
#define BM 128
#define BN 128
#define BK 16
__global__ void __launch_bounds__(256) xg_gemm(
    const float* __restrict__ emb, const int* __restrict__ ids,
    const float* __restrict__ w_f, const float* __restrict__ w_b,
    const float* __restrict__ bias, unsigned short* __restrict__ xg)
{
    __shared__ float As[BK][BM];
    __shared__ float Bs[BK][BN];
    __shared__ int rowtok[BM];
    int tid = threadIdx.x;
    int row0 = blockIdx.x * BM;
    int col0 = blockIdx.y * BN;
    if (tid < BM) rowtok[tid] = ids[row0 + tid];
    __syncthreads();

    int tx = tid & 15, ty = tid >> 4;
    float acc[8][8];
#pragma unroll
    for (int i = 0; i < 8; ++i)
#pragma unroll
        for (int j = 0; j < 8; ++j) acc[i][j] = 0.0f;

    for (int k0 = 0; k0 < EMB_; k0 += BK) {
#pragma unroll
        for (int l = 0; l < 2; ++l) {
            int idx = tid + l * 256;
            int r  = idx >> 2;
            int kc = (idx & 3) * 4;
            const float* src = emb + (size_t)rowtok[r] * EMB_ + k0 + kc;
            float4 v = *(const float4*)src;
            As[kc + 0][r] = v.x; As[kc + 1][r] = v.y;
            As[kc + 2][r] = v.z; As[kc + 3][r] = v.w;
        }
#pragma unroll
        for (int l = 0; l < 2; ++l) {
            int idx = tid + l * 256;
            int c  = idx >> 2;
            int kc = (idx & 3) * 4;
            int n  = col0 + c;
            const float* wr = (n < 1024) ? (w_f + (size_t)n * EMB_)
                                         : (w_b + (size_t)(n - 1024) * EMB_);
            float4 v = *(const float4*)(wr + k0 + kc);
            Bs[kc + 0][c] = v.x; Bs[kc + 1][c] = v.y;
            Bs[kc + 2][c] = v.z; Bs[kc + 3][c] = v.w;
        }
        __syncthreads();
#pragma unroll
        for (int k = 0; k < BK; ++k) {
            float a[8], b[8];
            *(float4*)&a[0] = *(float4*)&As[k][ty * 8];
            *(float4*)&a[4] = *(float4*)&As[k][ty * 8 + 4];
            *(float4*)&b[0] = *(float4*)&Bs[k][tx * 8];
            *(float4*)&b[4] = *(float4*)&Bs[k][tx * 8 + 4];
#pragma unroll
            for (int i = 0; i < 8; ++i)
#pragma unroll
                for (int j = 0; j < 8; ++j) acc[i][j] += a[i] * b[j];
        }
        __syncthreads();
    }
#pragma unroll
    for (int i = 0; i < 8; ++i) {
        size_t row = (size_t)row0 + ty * 8 + i;
#pragma unroll
        for (int j4 = 0; j4 < 2; ++j4) {
            int nb = col0 + tx * 8 + j4 * 4;
            ushort4 o;
            o.x = (unsigned short)f2bf(acc[i][j4 * 4 + 0] + bias[nb + 0]);
            o.y = (unsigned short)f2bf(acc[i][j4 * 4 + 1] + bias[nb + 1]);
            o.z = (unsigned short)f2bf(acc[i][j4 * 4 + 2] + bias[nb + 2]);
            o.w = (unsigned short)f2bf(acc[i][j4 * 4 + 3] + bias[nb + 3]);
            *(ushort4*)(xg + row * NG + nb) = o;
        }
    }
}

// ---------------------------------------------------------------------------
// Fused LSTM, 64 blocks x 512 threads: one block per (dir, 2-batch group).
// Full 1024x256 fp8 weight matrix register-resident per block (identical
// verified fragments as R6). MFMA M-rows 0..1 = the 2 batches (rows 2..15
// read permanently-zero LDS -> zero contribution). After MFMA, gates are
// redistributed through wave-private LDS (in-order per-wave DS pipe, no
// barrier needed) so all 64 lanes each update exactly ONE h. Two LDS-only
// barriers/step; zero cross-block traffic.
// ---------------------------------------------------------------------------
__global__ void __launch_bounds__(512, 1) lstm_fused(
    const unsigned short* __restrict__ xg,
    const unsigned long long* __restrict__ w8,   // fp8 [2][1024][256] as u64
    unsigned short* __restrict__ h_hist)         // bf16 [2*64][512][256]
{
    const int bid = blockIdx.x;          // 0..63
    const int dir = bid >> 5;
    const int bbase = (bid & 31) * 2;    // 2 batches per block
    const int tid = threadIdx.x;
    const int w = tid >> 6;              // wave 0..7: j-slice [w*32, w*32+32)
    const int l = tid & 63;
    const int l15 = l & 15, lq = l >> 4;

    __shared__ unsigned long long hbuf[16 * 33];   // fp8 h, rows 2..15 stay 0
    __shared__ float pg[8][4][2][32];              // [wave][gate][b][j-local]

    for (int i = tid; i < 16 * 33; i += 512) hbuf[i] = 0ull;

    // Stationary fp8 B fragments (verified layout):
    // rows n = g*256 + w*32 + nt*16 + l15, k = kt*32 + lq*8 .. +8
    unsigned long long bfrag[4][2][8];
    const unsigned long long* wbp = w8 + (size_t)dir * 32768;
#pragma unroll
    for (int g = 0; g < 4; ++g)
#pragma unroll
        for (int nt = 0; nt < 2; ++nt) {
            int row = g * 256 + w * 32 + nt * 16 + l15;
#pragma unroll
            for (int kt = 0; kt < 8; ++kt)
                bfrag[g][nt][kt] = wbp[row * 32 + kt * 4 + lq];
        }

    // Per-thread h ownership (update phase): b-local = l>>5, j = w*32 + (l&31)
    const int bl = l >> 5;
    const int jl = l & 31;
    const int j  = w * 32 + jl;
    const int bg = bbase + bl;           // batch within dir
    float cst = 0.0f;

    // xg prefetch (4 gates for this thread's (bg, j))
    unsigned short xq[4];
    {
        int t0 = dir ? (T_ - 1) : 0;
        const unsigned short* xp = xg + ((size_t)bg * T_ + t0) * NG + dir * 1024 + j;
#pragma unroll
        for (int g = 0; g < 4; ++g) xq[g] = xp[g * 256];
    }
    __syncthreads();   // hbuf zeros visible

    for (int s = 0; s < T_; ++s) {
        const int t = dir ? (T_ - 1 - s) : s;

        // A fragments: h(s-1) fp8 from LDS (m = l15 batch-row, k = kt*32+lq*8)
        unsigned long long af[8];
#pragma unroll
        for (int kt = 0; kt < 8; ++kt)
            af[kt] = hbuf[l15 * 33 + kt * 4 + lq];

        // MFMA: 64 per wave, acc rows 0..1 are the 2 real batches
        f32x4 acc[4][2];
#pragma unroll
        for (int g = 0; g < 4; ++g)
#pragma unroll
            for (int nt = 0; nt < 2; ++nt)
                acc[g][nt] = (f32x4){0.f, 0.f, 0.f, 0.f};
#pragma unroll
        for (int g = 0; g < 4; ++g)
#pragma unroll
            for (int nt = 0; nt < 2; ++nt)
#pragma unroll
                for (int kt = 0; kt < 8; ++kt)
                    acc[g][nt] = __builtin_amdgcn_mfma_f32_16x16x32_fp8_fp8(
                        (long long)af[kt], (long long)bfrag[g][nt][kt],
                        acc[g][nt], 0, 0, 0);

        // Redistribute gates via wave-private LDS (C/D row = lq*4+r -> rows
        // 0,1 live in lanes lq==0). Per-wave DS ops are in-order: the reads
        // below see these writes without a barrier.
        if (lq == 0) {
#pragma unroll
            for (int g = 0; g < 4; ++g)
#pragma unroll
                for (int nt = 0; nt < 2; ++nt) {
                    pg[w][g][0][nt * 16 + l15] = acc[g][nt][0];
                    pg[w][g][1][nt * 16 + l15] = acc[g][nt][1];
                }
        }
        float gi = pg[w][0][bl][jl] + bf2f(xq[0]);
        float gf = pg[w][1][bl][jl] + bf2f(xq[1]);
        float gg = pg[w][2][bl][jl] + bf2f(xq[2]);
        float go = pg[w][3][bl][jl] + bf2f(xq[3]);

        // prefetch next step's xg (latency hidden under update + barriers)
        {
            int sn = (s + 1 < T_) ? (s + 1) : s;
            int tn = dir ? (T_ - 1 - sn) : sn;
            const unsigned short* xp = xg + ((size_t)bg * T_ + tn) * NG + dir * 1024 + j;
#pragma unroll
            for (int g = 0; g < 4; ++g) xq[g] = xp[g * 256];
        }

        // cell update: exactly one h per lane
        float c = sigmf(gf) * cst + sigmf(gi) * tanh_fast(gg);
        cst = c;
        float h = sigmf(go) * tanh_fast(c);

        // global bf16 history store (async, no drain needed)
        h_hist[((size_t)(dir * 64 + bg) * T_ + t) * 256 + j] =
            (unsigned short)f2bf(h);

        bar_lds();   // all waves done reading hbuf (af) before overwrite
        unsigned int p8 = __builtin_amdgcn_cvt_pk_fp8_f32(h, h, 0, false);
        ((unsigned char*)hbuf)[bl * 264 + j] = (unsigned char)(p8 & 0xffu);
        bar_lds();   // hbuf writes visible before next step's af reads
    }
}

// ---------------------------------------------------------------------------
// Emissions (reads bf16 h history)
// ---------------------------------------------------------------------------
__global__ void __launch_bounds__(256) emis_k(
    const unsigned short* __restrict__ h_hist, const float* __restrict__ w_cls,
    const float* __restrict__ b_cls, float* __restrict__ em)
{
    int wid = threadIdx.x >> 6, lane = threadIdx.x & 63;
    size_t row = (size_t)blockIdx.x * 4 + wid;       // b*T + t
    const unsigned short* hf = h_hist + row * 256;
    const unsigned short* hb = h_hist + (size_t)64 * 512 * 256 + row * 256;
    ushort4 u0 = *(const ushort4*)(hf + 4 * lane);
    ushort4 u1 = *(const ushort4*)(hb + 4 * lane);
    float a0x = bf2f(u0.x), a0y = bf2f(u0.y), a0z = bf2f(u0.z), a0w = bf2f(u0.w);
    float a1x = bf2f(u1.x), a1y = bf2f(u1.y), a1z = bf2f(u1.z), a1w = bf2f(u1.w);
#pragma unroll
    for (int l = 0; l < L_; ++l) {
        const float* wr = w_cls + (size_t)l * 512;
        float4 w0 = *(const float4*)(wr + 4 * lane);
        float4 w1 = *(const float4*)(wr + 256 + 4 * lane);
        float d = a0x * w0.x + a0y * w0.y + a0z * w0.z + a0w * w0.w
                + a1x * w1.x + a1y * w1.y + a1z * w1.z + a1w * w1.w;
#pragma unroll
        for (int off = 32; off; off >>= 1) d += __shfl_down(d, off);
        if (lane == 0) em[row * L_ + l] = d + b_cls[l];
    }
}

// ---------------------------------------------------------------------------
// CRF NLL
// ---------------------------------------------------------------------------
__global__ void __launch_bounds__(64) crf_k(
    const float* __restrict__ em, const int* __restrict__ labels,
    const int* __restrict__ mask, const float* __restrict__ trans,
    const float* __restrict__ startv, const float* __restrict__ endv,
    float* __restrict__ out)
{
    int b = blockIdx.x, lane = threadIdx.x;
    const float* emb_ = em + (size_t)b * T_ * L_;
    const int* lab = labels + (size_t)b * T_;
    const int* msk = mask + (size_t)b * T_;
    __shared__ float alpha[L_];
    __shared__ float trs[81];
    for (int i = lane; i < 81; i += 64) trs[i] = trans[i];
    __syncthreads();

    float np = 0.0f;
    for (int t = 1 + lane; t < T_; t += 64)
        if (msk[t]) np += trs[lab[t - 1] * L_ + lab[t]] + emb_[(size_t)t * L_ + lab[t]];
    int mc = 0;
    for (int t = lane; t < T_; t += 64) mc += (msk[t] != 0);
#pragma unroll
    for (int off = 32; off; off >>= 1) {
        np += __shfl_down(np, off);
        mc += __shfl_down(mc, off);
    }
    float num = 0.0f;
    if (lane == 0) {
        int last = mc - 1;
        num = np + startv[lab[0]] + emb_[lab[0]] + endv[lab[last]];
    }

    if (lane < L_) alpha[lane] = startv[lane] + emb_[lane];
    __syncthreads();
    for (int t = 1; t < T_; ++t) {
        float na = 0.0f;
        if (lane < L_) {
            float m = -1e30f;
#pragma unroll
            for (int i = 0; i < L_; ++i) m = fmaxf(m, alpha[i] + trs[i * L_ + lane]);
            float s = 0.0f;
#pragma unroll
            for (int i = 0; i < L_; ++i) s += __expf(alpha[i] + trs[i * L_ + lane] - m);
            na = m + __logf(s) + emb_[(size_t)t * L_ + lane];
            if (!msk[t]) na = alpha[lane];
        }
        __syncthreads();
        if (lane < L_) alpha[lane] = na;
        __syncthreads();
    }
    float v = (lane < L_) ? alpha[lane] + endv[lane] : -1e30f;
    float m = v;
#pragma unroll
    for (int off = 32; off; off >>= 1) m = fmaxf(m, __shfl_xor(m, off));
    float s = (lane < L_) ? __expf(v - m) : 0.0f;
#pragma unroll
    for (int off = 32; off; off >>= 1) s += __shfl_xor(s, off);
    if (lane == 0) {
        float logZ = m + __logf(s);
        atomicAdd(out, (logZ - num) / (float)B_);
    }
}

__global__ void zero_out_k(float* out) { out[0] = 0.0f; }
__global__ void ws_fail_k(float* out, float v) { out[0] = v; }

// ---------------------------------------------------------------------------
extern "C" void kernel_launch(void* const* d_in, const int* in_sizes, int n_in,
                              void* d_out, int out_size, void* d_ws, size_t ws_size,
                              hipStream_t stream)
{
    const int*   ids    = (const int*)  d_in[0];
    const int*   amask  = (const int*)  d_in[1];
    const int*   labels = (const int*)  d_in[2];
    const float* emb    = (const float*)d_in[3];
    const float* w_ih_f = (const float*)d_in[4];
    const float* w_hh_f = (const float*)d_in[5];
    const float* b_ih_f = (const float*)d_in[6];
    const float* b_hh_f = (const float*)d_in[7];
    const float* w_ih_b = (const float*)d_in[8];
    const float* w_hh_b = (const float*)d_in[9];
    const float* b_ih_b = (const float*)d_in[10];
    const float* b_hh_b = (const float*)d_in[11];
    const float* w_cls  = (const float*)d_in[12];
    const float* b_cls  = (const float*)d_in[13];
    const float* trans  = (const float*)d_in[14];
    const float* startv = (const float*)d_in[15];
    const float* endv   = (const float*)d_in[16];
    float* out = (float*)d_out;

    // workspace layout
    size_t o_xg   = 0;                                   // bf16 xg: 128 MB
    size_t o_bias = o_xg + (size_t)NROW * NG * 2;
    size_t o_w8   = o_bias + 2048 * 4;                   // fp8 weights: 512 KB
    size_t o_hh   = o_w8 + (size_t)2 * 1024 * 256;       // h_hist: 32 MB
    size_t o_em   = o_hh + (size_t)2 * B_ * T_ * H_ * 2;
    size_t total  = o_em + (size_t)NROW * L_ * 4;

    if (ws_size < total) {
        ws_fail_k<<<1, 1, 0, stream>>>(out, -1.0e8f - (float)(ws_size >> 20));
        return;
    }

    unsigned short* xg       = (unsigned short*)((char*)d_ws + o_xg);
    float* bias              = (float*)((char*)d_ws + o_bias);
    unsigned int* w8         = (unsigned int*)((char*)d_ws + o_w8);
    unsigned short* h_hist   = (unsigned short*)((char*)d_ws + o_hh);
    float* em                = (float*)((char*)d_ws + o_em);

    bias_k<<<8, 256, 0, stream>>>(b_ih_f, b_hh_f, b_ih_b, b_hh_b, bias);
    prep_w8<<<512, 256, 0, stream>>>(w_hh_f, w_hh_b, w8);
    xg_gemm<<<dim3(NROW / BM, NG / BN), 256, 0, stream>>>(emb, ids, w_ih_f, w_ih_b, bias, xg);
    lstm_fused<<<64, 512, 0, stream>>>(xg, (const unsigned long long*)w8, h_hist);
    emis_k<<<NROW / 4, 256, 0, stream>>>(h_hist, w_cls, b_cls, em);
    zero_out_k<<<1, 1, 0, stream>>>(out);
    crf_k<<<B_, 64, 0, stream>>>(em, labels, amask, trans, startv, endv, out);
}

// Round 9
// 1076.976 us; speedup vs baseline: 1.7885x; 1.1861x over previous
//
#include <hip/hip_runtime.h>
#include <hip/hip_bf16.h>

// Problem constants
#define B_   64
#define T_   512
#define EMB_ 256
#define H_   256          // hidden per direction
#define L_   9
#define NROW (B_*T_)      // 32768
#define NG   2048         // both directions' gates

typedef __attribute__((ext_vector_type(4))) float f32x4;
typedef __attribute__((ext_vector_type(8))) short bf16x8;

__device__ __forceinline__ float bf2f(unsigned short u) {
    union { unsigned int i; float f; } c; c.i = ((unsigned int)u) << 16; return c.f;
}
__device__ __forceinline__ unsigned int f2bf(float f) {
    union { unsigned int i; float f; } c; c.f = f;
    unsigned int i = c.i;
    return (i + 0x7FFFu + ((i >> 16) & 1u)) >> 16;
}
__device__ __forceinline__ float sigmf(float x) {
    return __builtin_amdgcn_rcpf(1.0f + __expf(-x));
}
__device__ __forceinline__ float tanh_fast(float x) {
    return 2.0f * __builtin_amdgcn_rcpf(1.0f + __expf(-2.0f * x)) - 1.0f;
}
// Raw block barrier ordering LDS only.
__device__ __forceinline__ void bar_lds() {
    asm volatile("s_waitcnt lgkmcnt(0)\n\ts_barrier" ::: "memory");
}

// ---------------------------------------------------------------------------
// bias[n] = b_ih + b_hh (both dirs)
// ---------------------------------------------------------------------------
__global__ void __launch_bounds__(256) bias_k(
    const float* __restrict__ bihf, const float* __restrict__ bhhf,
    const float* __restrict__ bihb, const float* __restrict__ bhhb,
    float* __restrict__ bias)
{
    int i = blockIdx.x * 256 + threadIdx.x;   // 0..2047
    if (i < 1024) bias[i] = bihf[i] + bhhf[i];
    else          bias[i] = bihb[i - 1024] + bhhb[i - 1024];
}

// ---------------------------------------------------------------------------
// Convert w_hh (both dirs) to fp8 e4m3, same row-major [1024][256] layout.
// ---------------------------------------------------------------------------
__global__ void __launch_bounds__(256) prep_w8(
    const float* __restrict__ wf, const float* __restrict__ wb,
    unsigned int* __restrict__ w8)
{
    int i = blockIdx.x * 256 + threadIdx.x;   // word index, 131072 total
    const float* src = (i < 65536) ? wf : wb;
    int j = (i & 65535) * 4;
    unsigned int pk = __builtin_amdgcn_cvt_pk_fp8_f32(src[j], src[j + 1], 0, false);
    pk = __builtin_amdgcn_cvt_pk_fp8_f32(src[j + 2], src[j + 3], pk, true);
    w8[i] = pk;
}

// ---------------------------------------------------------------------------
// xg GEMM via bf16 MFMA: xg[row][n] = emb[ids[row]] . w(n) + bias[n]  (bf16)
// 128x128 tile, 4 waves (64x64 subtile each), K staged in 2 halves of 128,
// fp32->bf16 conversion done in staging. Verified fragment layouts:
//   A/B input: m/n = l&15, k = (l>>4)*8 + e ; C/D: row = (l>>4)*4+r, col = l&15
// LDS rows padded to 136 bf16 (bank stride 4 -> conflict-free ds_read_b128).
// ---------------------------------------------------------------------------
#define XBK 128
__global__ void __launch_bounds__(256, 2) xg_gemm_mfma(
    const float* __restrict__ emb, const int* __restrict__ ids,
    const float* __restrict__ w_f, const float* __restrict__ w_b,
    const float* __restrict__ bias, unsigned short* __restrict__ xg)
{
    __shared__ unsigned short A_lds[128][XBK + 8];
    __shared__ unsigned short B_lds[128][XBK + 8];
    __shared__ int rowtok[128];

    const int tid = threadIdx.x;
    const int row0 = blockIdx.x * 128;
    const int col0 = blockIdx.y * 128;
    const int w  = tid >> 6;             // wave 0..3
    const int wr = w >> 1, wc = w & 1;   // 64x64 subtile coords
    const int l  = tid & 63;
    const int l15 = l & 15, lq = l >> 4;

    if (tid < 128) rowtok[tid] = ids[row0 + tid];
    __syncthreads();

    f32x4 acc[4][4];
#pragma unroll
    for (int mt = 0; mt < 4; ++mt)
#pragma unroll
        for (int nt = 0; nt < 4; ++nt)
            acc[mt][nt] = (f32x4){0.f, 0.f, 0.f, 0.f};

    for (int kh = 0; kh < 2; ++kh) {
        // stage A (gathered emb rows) and B (gate weight rows), fp32 -> bf16
#pragma unroll
        for (int i = 0; i < 16; ++i) {
            int c = tid + i * 256;            // 0..4095
            int r = c >> 5, k4 = (c & 31) * 4;
            const float* src = emb + (size_t)rowtok[r] * EMB_ + kh * XBK + k4;
            float4 v = *(const float4*)src;
            ushort4 o;
            o.x = (unsigned short)f2bf(v.x); o.y = (unsigned short)f2bf(v.y);
            o.z = (unsigned short)f2bf(v.z); o.w = (unsigned short)f2bf(v.w);
            *(ushort4*)&A_lds[r][k4] = o;
        }
#pragma unroll
        for (int i = 0; i < 16; ++i) {
            int c = tid + i * 256;
            int r = c >> 5, k4 = (c & 31) * 4;
            int n = col0 + r;
            const float* wrow = (n < 1024) ? (w_f + (size_t)n * EMB_)
                                           : (w_b + (size_t)(n - 1024) * EMB_);
            float4 v = *(const float4*)(wrow + kh * XBK + k4);
            ushort4 o;
            o.x = (unsigned short)f2bf(v.x); o.y = (unsigned short)f2bf(v.y);
            o.z = (unsigned short)f2bf(v.z); o.w = (unsigned short)f2bf(v.w);
            *(ushort4*)&B_lds[r][k4] = o;
        }
        __syncthreads();

#pragma unroll
        for (int kt = 0; kt < 4; ++kt) {
            bf16x8 a[4], b[4];
#pragma unroll
            for (int mt = 0; mt < 4; ++mt)
                a[mt] = *(const bf16x8*)&A_lds[wr * 64 + mt * 16 + l15][kt * 32 + lq * 8];
#pragma unroll
            for (int nt = 0; nt < 4; ++nt)
                b[nt] = *(const bf16x8*)&B_lds[wc * 64 + nt * 16 + l15][kt * 32 + lq * 8];
#pragma unroll
            for (int mt = 0; mt < 4; ++mt)
#pragma unroll
                for (int nt = 0; nt < 4; ++nt)
                    acc[mt][nt] = __builtin_amdgcn_mfma_f32_16x16x32_bf16(
                        a[mt], b[nt], acc[mt][nt], 0, 0, 0);
        }
        __syncthreads();
    }

    // epilogue: + bias, bf16 store (C/D: row = lq*4+r, col = l15)
    float bv[4];
#pragma unroll
    for (int nt = 0; nt < 4; ++nt)
        bv[nt] = bias[col0 + wc * 64 + nt * 16 + l15];
#pragma unroll
    for (int mt = 0; mt < 4; ++mt)
#pragma unroll
        for (int r = 0; r < 4; ++r) {
            size_t row = (size_t)row0 + wr * 64 + mt * 16 + lq * 4 + r;
#pragma unroll
            for (int nt = 0; nt < 4; ++nt) {
                int col = col0 + wc * 64 + nt * 16 + l15;
                xg[row * NG + col] = (unsigned short)f2bf(acc[mt][nt][r] + bv[nt]);
            }
        }
}

// ---------------------------------------------------------------------------
// Fused LSTM, 64 blocks x 512 threads: one block per (dir, 2-batch group).
// (unchanged from R7 — verified)
// ---------------------------------------------------------------------------
__global__ void __launch_bounds__(512, 1) lstm_fused(
    const unsigned short* __restrict__ xg,
    const unsigned long long* __restrict__ w8,   // fp8 [2][1024][256] as u64
    unsigned short* __restrict__ h_hist)         // bf16 [2*64][512][256]
{
    const int bid = blockIdx.x;          // 0..63
    const int dir = bid >> 5;
    const int bbase = (bid & 31) * 2;    // 2 batches per block
    const int tid = threadIdx.x;
    const int w = tid >> 6;              // wave 0..7: j-slice [w*32, w*32+32)
    const int l = tid & 63;
    const int l15 = l & 15, lq = l >> 4;

    __shared__ unsigned long long hbuf[16 * 33];   // fp8 h, rows 2..15 stay 0
    __shared__ float pg[8][4][2][32];              // [wave][gate][b][j-local]

    for (int i = tid; i < 16 * 33; i += 512) hbuf[i] = 0ull;

    // Stationary fp8 B fragments (verified layout):
    // rows n = g*256 + w*32 + nt*16 + l15, k = kt*32 + lq*8 .. +8
    unsigned long long bfrag[4][2][8];
    const unsigned long long* wbp = w8 + (size_t)dir * 32768;
#pragma unroll
    for (int g = 0; g < 4; ++g)
#pragma unroll
        for (int nt = 0; nt < 2; ++nt) {
            int row = g * 256 + w * 32 + nt * 16 + l15;
#pragma unroll
            for (int kt = 0; kt < 8; ++kt)
                bfrag[g][nt][kt] = wbp[row * 32 + kt * 4 + lq];
        }

    // Per-thread h ownership (update phase): b-local = l>>5, j = w*32 + (l&31)
    const int bl = l >> 5;
    const int jl = l & 31;
    const int j  = w * 32 + jl;
    const int bg = bbase + bl;           // batch within dir
    float cst = 0.0f;

    // xg prefetch (4 gates for this thread's (bg, j))
    unsigned short xq[4];
    {
        int t0 = dir ? (T_ - 1) : 0;
        const unsigned short* xp = xg + ((size_t)bg * T_ + t0) * NG + dir * 1024 + j;
#pragma unroll
        for (int g = 0; g < 4; ++g) xq[g] = xp[g * 256];
    }
    __syncthreads();   // hbuf zeros visible

    for (int s = 0; s < T_; ++s) {
        const int t = dir ? (T_ - 1 - s) : s;

        // A fragments: h(s-1) fp8 from LDS (m = l15 batch-row, k = kt*32+lq*8)
        unsigned long long af[8];
#pragma unroll
        for (int kt = 0; kt < 8; ++kt)
            af[kt] = hbuf[l15 * 33 + kt * 4 + lq];

        // MFMA: 64 per wave, acc rows 0..1 are the 2 real batches
        f32x4 acc[4][2];
#pragma unroll
        for (int g = 0; g < 4; ++g)
#pragma unroll
            for (int nt = 0; nt < 2; ++nt)
                acc[g][nt] = (f32x4){0.f, 0.f, 0.f, 0.f};
#pragma unroll
        for (int g = 0; g < 4; ++g)
#pragma unroll
            for (int nt = 0; nt < 2; ++nt)
#pragma unroll
                for (int kt = 0; kt < 8; ++kt)
                    acc[g][nt] = __builtin_amdgcn_mfma_f32_16x16x32_fp8_fp8(
                        (long long)af[kt], (long long)bfrag[g][nt][kt],
                        acc[g][nt], 0, 0, 0);

        // Redistribute gates via wave-private LDS (C/D row = lq*4+r -> rows
        // 0,1 live in lanes lq==0). Per-wave DS ops are in-order: the reads
        // below see these writes without a barrier.
        if (lq == 0) {
#pragma unroll
            for (int g = 0; g < 4; ++g)
#pragma unroll
                for (int nt = 0; nt < 2; ++nt) {
                    pg[w][g][0][nt * 16 + l15] = acc[g][nt][0];
                    pg[w][g][1][nt * 16 + l15] = acc[g][nt][1];
                }
        }
        float gi = pg[w][0][bl][jl] + bf2f(xq[0]);
        float gf = pg[w][1][bl][jl] + bf2f(xq[1]);
        float gg = pg[w][2][bl][jl] + bf2f(xq[2]);
        float go = pg[w][3][bl][jl] + bf2f(xq[3]);

        // prefetch next step's xg (latency hidden under update + barriers)
        {
            int sn = (s + 1 < T_) ? (s + 1) : s;
            int tn = dir ? (T_ - 1 - sn) : sn;
            const unsigned short* xp = xg + ((size_t)bg * T_ + tn) * NG + dir * 1024 + j;
#pragma unroll
            for (int g = 0; g < 4; ++g) xq[g] = xp[g * 256];
        }

        // cell update: exactly one h per lane
        float c = sigmf(gf) * cst + sigmf(gi) * tanh_fast(gg);
        cst = c;
        float h = sigmf(go) * tanh_fast(c);

        // global bf16 history store (async, no drain needed)
        h_hist[((size_t)(dir * 64 + bg) * T_ + t) * 256 + j] =
            (unsigned short)f2bf(h);

        bar_lds();   // all waves done reading hbuf (af) before overwrite
        unsigned int p8 = __builtin_amdgcn_cvt_pk_fp8_f32(h, h, 0, false);
        ((unsigned char*)hbuf)[bl * 264 + j] = (unsigned char)(p8 & 0xffu);
        bar_lds();   // hbuf writes visible before next step's af reads
    }
}

// ---------------------------------------------------------------------------
// Emissions (reads bf16 h history)
// ---------------------------------------------------------------------------
__global__ void __launch_bounds__(256) emis_k(
    const unsigned short* __restrict__ h_hist, const float* __restrict__ w_cls,
    const float* __restrict__ b_cls, float* __restrict__ em)
{
    int wid = threadIdx.x >> 6, lane = threadIdx.x & 63;
    size_t row = (size_t)blockIdx.x * 4 + wid;       // b*T + t
    const unsigned short* hf = h_hist + row * 256;
    const unsigned short* hb = h_hist + (size_t)64 * 512 * 256 + row * 256;
    ushort4 u0 = *(const ushort4*)(hf + 4 * lane);
    ushort4 u1 = *(const ushort4*)(hb + 4 * lane);
    float a0x = bf2f(u0.x), a0y = bf2f(u0.y), a0z = bf2f(u0.z), a0w = bf2f(u0.w);
    float a1x = bf2f(u1.x), a1y = bf2f(u1.y), a1z = bf2f(u1.z), a1w = bf2f(u1.w);
#pragma unroll
    for (int l = 0; l < L_; ++l) {
        const float* wr = w_cls + (size_t)l * 512;
        float4 w0 = *(const float4*)(wr + 4 * lane);
        float4 w1 = *(const float4*)(wr + 256 + 4 * lane);
        float d = a0x * w0.x + a0y * w0.y + a0z * w0.z + a0w * w0.w
                + a1x * w1.x + a1y * w1.y + a1z * w1.z + a1w * w1.w;
#pragma unroll
        for (int off = 32; off; off >>= 1) d += __shfl_down(d, off);
        if (lane == 0) em[row * L_ + l] = d + b_cls[l];
    }
}

// ---------------------------------------------------------------------------
// CRF NLL
// ---------------------------------------------------------------------------
__global__ void __launch_bounds__(64) crf_k(
    const float* __restrict__ em, const int* __restrict__ labels,
    const int* __restrict__ mask, const float* __restrict__ trans,
    const float* __restrict__ startv, const float* __restrict__ endv,
    float* __restrict__ out)
{
    int b = blockIdx.x, lane = threadIdx.x;
    const float* emb_ = em + (size_t)b * T_ * L_;
    const int* lab = labels + (size_t)b * T_;
    const int* msk = mask + (size_t)b * T_;
    __shared__ float alpha[L_];
    __shared__ float trs[81];
    for (int i = lane; i < 81; i += 64) trs[i] = trans[i];
    __syncthreads();

    float np = 0.0f;
    for (int t = 1 + lane; t < T_; t += 64)
        if (msk[t]) np += trs[lab[t - 1] * L_ + lab[t]] + emb_[(size_t)t * L_ + lab[t]];
    int mc = 0;
    for (int t = lane; t < T_; t += 64) mc += (msk[t] != 0);
#pragma unroll
    for (int off = 32; off; off >>= 1) {
        np += __shfl_down(np, off);
        mc += __shfl_down(mc, off);
    }
    float num = 0.0f;
    if (lane == 0) {
        int last = mc - 1;
        num = np + startv[lab[0]] + emb_[lab[0]] + endv[lab[last]];
    }

    if (lane < L_) alpha[lane] = startv[lane] + emb_[lane];
    __syncthreads();
    for (int t = 1; t < T_; ++t) {
        float na = 0.0f;
        if (lane < L_) {
            float m = -1e30f;
#pragma unroll
            for (int i = 0; i < L_; ++i) m = fmaxf(m, alpha[i] + trs[i * L_ + lane]);
            float s = 0.0f;
#pragma unroll
            for (int i = 0; i < L_; ++i) s += __expf(alpha[i] + trs[i * L_ + lane] - m);
            na = m + __logf(s) + emb_[(size_t)t * L_ + lane];
            if (!msk[t]) na = alpha[lane];
        }
        __syncthreads();
        if (lane < L_) alpha[lane] = na;
        __syncthreads();
    }
    float v = (lane < L_) ? alpha[lane] + endv[lane] : -1e30f;
    float m = v;
#pragma unroll
    for (int off = 32; off; off >>= 1) m = fmaxf(m, __shfl_xor(m, off));
    float s = (lane < L_) ? __expf(v - m) : 0.0f;
#pragma unroll
    for (int off = 32; off; off >>= 1) s += __shfl_xor(s, off);
    if (lane == 0) {
        float logZ = m + __logf(s);
        atomicAdd(out, (logZ - num) / (float)B_);
    }
}

__global__ void zero_out_k(float* out) { out[0] = 0.0f; }
__global__ void ws_fail_k(float* out, float v) { out[0] = v; }

// ---------------------------------------------------------------------------
extern "C" void kernel_launch(void* const* d_in, const int* in_sizes, int n_in,
                              void* d_out, int out_size, void* d_ws, size_t ws_size,
                              hipStream_t stream)
{
    const int*   ids    = (const int*)  d_in[0];
    const int*   amask  = (const int*)  d_in[1];
    const int*   labels = (const int*)  d_in[2];
    const float* emb    = (const float*)d_in[3];
    const float* w_ih_f = (const float*)d_in[4];
    const float* w_hh_f = (const float*)d_in[5];
    const float* b_ih_f = (const float*)d_in[6];
    const float* b_hh_f = (const float*)d_in[7];
    const float* w_ih_b = (const float*)d_in[8];
    const float* w_hh_b = (const float*)d_in[9];
    const float* b_ih_b = (const float*)d_in[10];
    const float* b_hh_b = (const float*)d_in[11];
    const float* w_cls  = (const float*)d_in[12];
    const float* b_cls  = (const float*)d_in[13];
    const float* trans  = (const float*)d_in[14];
    const float* startv = (const float*)d_in[15];
    const float* endv   = (const float*)d_in[16];
    float* out = (float*)d_out;

    // workspace layout
    size_t o_xg   = 0;                                   // bf16 xg: 128 MB
    size_t o_bias = o_xg + (size_t)NROW * NG * 2;
    size_t o_w8   = o_bias + 2048 * 4;                   // fp8 weights: 512 KB
    size_t o_hh   = o_w8 + (size_t)2 * 1024 * 256;       // h_hist: 32 MB
    size_t o_em   = o_hh + (size_t)2 * B_ * T_ * H_ * 2;
    size_t total  = o_em + (size_t)NROW * L_ * 4;

    if (ws_size < total) {
        ws_fail_k<<<1, 1, 0, stream>>>(out, -1.0e8f - (float)(ws_size >> 20));
        return;
    }

    unsigned short* xg       = (unsigned short*)((char*)d_ws + o_xg);
    float* bias              = (float*)((char*)d_ws + o_bias);
    unsigned int* w8         = (unsigned int*)((char*)d_ws + o_w8);
    unsigned short* h_hist   = (unsigned short*)((char*)d_ws + o_hh);
    float* em                = (float*)((char*)d_ws + o_em);

    bias_k<<<8, 256, 0, stream>>>(b_ih_f, b_hh_f, b_ih_b, b_hh_b, bias);
    prep_w8<<<512, 256, 0, stream>>>(w_hh_f, w_hh_b, w8);
    xg_gemm_mfma<<<dim3(NROW / 128, NG / 128), 256, 0, stream>>>(
        emb, ids, w_ih_f, w_ih_b, bias, xg);
    lstm_fused<<<64, 512, 0, stream>>>(xg, (const unsigned long long*)w8, h_hist);
    emis_k<<<NROW / 4, 256, 0, stream>>>(h_hist, w_cls, b_cls, em);
    zero_out_k<<<1, 1, 0, stream>>>(out);
    crf_k<<<B_, 64, 0, stream>>>(em, labels, amask, trans, startv, endv, out);
}

// Round 10
// 814.848 us; speedup vs baseline: 2.3638x; 1.3217x over previous
//
#include <hip/hip_runtime.h>
#include <hip/hip_bf16.h>

// Problem constants
#define B_   64
#define T_   512
#define EMB_ 256
#define H_   256          // hidden per direction
#define L_   9
#define NROW (B_*T_)      // 32768
#define NG   2048         // both directions' gates

typedef __attribute__((ext_vector_type(4))) float f32x4;
typedef __attribute__((ext_vector_type(8))) short bf16x8;
typedef __attribute__((ext_vector_type(8))) int i32x8;

__device__ __forceinline__ float bf2f(unsigned short u) {
    union { unsigned int i; float f; } c; c.i = ((unsigned int)u) << 16; return c.f;
}
__device__ __forceinline__ unsigned int f2bf(float f) {
    union { unsigned int i; float f; } c; c.f = f;
    unsigned int i = c.i;
    return (i + 0x7FFFu + ((i >> 16) & 1u)) >> 16;
}
__device__ __forceinline__ float sigmf(float x) {
    return __builtin_amdgcn_rcpf(1.0f + __expf(-x));
}
__device__ __forceinline__ float tanh_fast(float x) {
    return 2.0f * __builtin_amdgcn_rcpf(1.0f + __expf(-2.0f * x)) - 1.0f;
}
// Raw block barrier ordering LDS only.
__device__ __forceinline__ void bar_lds() {
    asm volatile("s_waitcnt lgkmcnt(0)\n\ts_barrier" ::: "memory");
}

// ---------------------------------------------------------------------------
// bias[n] = b_ih + b_hh (both dirs)
// ---------------------------------------------------------------------------
__global__ void __launch_bounds__(256) bias_k(
    const float* __restrict__ bihf, const float* __restrict__ bhhf,
    const float* __restrict__ bihb, const float* __restrict__ bhhb,
    float* __restrict__ bias)
{
    int i = blockIdx.x * 256 + threadIdx.x;   // 0..2047
    if (i < 1024) bias[i] = bihf[i] + bhhf[i];
    else          bias[i] = bihb[i - 1024] + bhhb[i - 1024];
}

// ---------------------------------------------------------------------------
// Convert w_hh (both dirs) to fp8 e4m3, same row-major [1024][256] layout.
// ---------------------------------------------------------------------------
__global__ void __launch_bounds__(256) prep_w8(
    const float* __restrict__ wf, const float* __restrict__ wb,
    unsigned int* __restrict__ w8)
{
    int i = blockIdx.x * 256 + threadIdx.x;   // word index, 131072 total
    const float* src = (i < 65536) ? wf : wb;
    int j = (i & 65535) * 4;
    unsigned int pk = __builtin_amdgcn_cvt_pk_fp8_f32(src[j], src[j + 1], 0, false);
    pk = __builtin_amdgcn_cvt_pk_fp8_f32(src[j + 2], src[j + 3], pk, true);
    w8[i] = pk;
}

// ---------------------------------------------------------------------------
// xg GEMM via bf16 MFMA (unchanged from R8 — verified)
// ---------------------------------------------------------------------------
#define XBK 128
__global__ void __launch_bounds__(256, 2) xg_gemm_mfma(
    const float* __restrict__ emb, const int* __restrict__ ids,
    const float* __restrict__ w_f, const float* __restrict__ w_b,
    const float* __restrict__ bias, unsigned short* __restrict__ xg)
{
    __shared__ unsigned short A_lds[128][XBK + 8];
    __shared__ unsigned short B_lds[128][XBK + 8];
    __shared__ int rowtok[128];

    const int tid = threadIdx.x;
    const int row0 = blockIdx.x * 128;
    const int col0 = blockIdx.y * 128;
    const int w  = tid >> 6;             // wave 0..3
    const int wr = w >> 1, wc = w & 1;   // 64x64 subtile coords
    const int l  = tid & 63;
    const int l15 = l & 15, lq = l >> 4;

    if (tid < 128) rowtok[tid] = ids[row0 + tid];
    __syncthreads();

    f32x4 acc[4][4];
#pragma unroll
    for (int mt = 0; mt < 4; ++mt)
#pragma unroll
        for (int nt = 0; nt < 4; ++nt)
            acc[mt][nt] = (f32x4){0.f, 0.f, 0.f, 0.f};

    for (int kh = 0; kh < 2; ++kh) {
#pragma unroll
        for (int i = 0; i < 16; ++i) {
            int c = tid + i * 256;            // 0..4095
            int r = c >> 5, k4 = (c & 31) * 4;
            const float* src = emb + (size_t)rowtok[r] * EMB_ + kh * XBK + k4;
            float4 v = *(const float4*)src;
            ushort4 o;
            o.x = (unsigned short)f2bf(v.x); o.y = (unsigned short)f2bf(v.y);
            o.z = (unsigned short)f2bf(v.z); o.w = (unsigned short)f2bf(v.w);
            *(ushort4*)&A_lds[r][k4] = o;
        }
#pragma unroll
        for (int i = 0; i < 16; ++i) {
            int c = tid + i * 256;
            int r = c >> 5, k4 = (c & 31) * 4;
            int n = col0 + r;
            const float* wrow = (n < 1024) ? (w_f + (size_t)n * EMB_)
                                           : (w_b + (size_t)(n - 1024) * EMB_);
            float4 v = *(const float4*)(wrow + kh * XBK + k4);
            ushort4 o;
            o.x = (unsigned short)f2bf(v.x); o.y = (unsigned short)f2bf(v.y);
            o.z = (unsigned short)f2bf(v.z); o.w = (unsigned short)f2bf(v.w);
            *(ushort4*)&B_lds[r][k4] = o;
        }
        __syncthreads();

#pragma unroll
        for (int kt = 0; kt < 4; ++kt) {
            bf16x8 a[4], b[4];
#pragma unroll
            for (int mt = 0; mt < 4; ++mt)
                a[mt] = *(const bf16x8*)&A_lds[wr * 64 + mt * 16 + l15][kt * 32 + lq * 8];
#pragma unroll
            for (int nt = 0; nt < 4; ++nt)
                b[nt] = *(const bf16x8*)&B_lds[wc * 64 + nt * 16 + l15][kt * 32 + lq * 8];
#pragma unroll
            for (int mt = 0; mt < 4; ++mt)
#pragma unroll
                for (int nt = 0; nt < 4; ++nt)
                    acc[mt][nt] = __builtin_amdgcn_mfma_f32_16x16x32_bf16(
                        a[mt], b[nt], acc[mt][nt], 0, 0, 0);
        }
        __syncthreads();
    }

    float bv[4];
#pragma unroll
    for (int nt = 0; nt < 4; ++nt)
        bv[nt] = bias[col0 + wc * 64 + nt * 16 + l15];
#pragma unroll
    for (int mt = 0; mt < 4; ++mt)
#pragma unroll
        for (int r = 0; r < 4; ++r) {
            size_t row = (size_t)row0 + wr * 64 + mt * 16 + lq * 4 + r;
#pragma unroll
            for (int nt = 0; nt < 4; ++nt) {
                int col = col0 + wc * 64 + nt * 16 + l15;
                xg[row * NG + col] = (unsigned short)f2bf(acc[mt][nt][r] + bv[nt]);
            }
        }
}

// ---------------------------------------------------------------------------
// Fused LSTM, 64 blocks x 512 threads: one block per (dir, 2-batch group).
// R9: inner product via MX-scaled fp8 K=128 MFMA (scales = 1.0), 16 instr
// per wave-step instead of 64 non-scaled K=32 (2.28x matrix throughput).
// A/B loaded with the SAME assumed k-mapping (k = half*128 + lq*32 + e), so
// any HW k-permutation cancels in the dot product; scales=1.0 make scale-
// block alignment irrelevant. C/D layout shape-determined (verified).
// ---------------------------------------------------------------------------
__global__ void __launch_bounds__(512, 1) lstm_fused(
    const unsigned short* __restrict__ xg,
    const unsigned long long* __restrict__ w8,   // fp8 [2][1024][256] as u64
    unsigned short* __restrict__ h_hist)         // bf16 [2*64][512][256]
{
    const int bid = blockIdx.x;          // 0..63
    const int dir = bid >> 5;
    const int bbase = (bid & 31) * 2;    // 2 batches per block
    const int tid = threadIdx.x;
    const int w = tid >> 6;              // wave 0..7: j-slice [w*32, w*32+32)
    const int l = tid & 63;
    const int l15 = l & 15, lq = l >> 4;

    __shared__ unsigned long long hbuf[16 * 33];   // fp8 h, rows 2..15 stay 0
    __shared__ float pg[8][4][2][32];              // [wave][gate][b][j-local]

    for (int i = tid; i < 16 * 33; i += 512) hbuf[i] = 0ull;

    // Stationary fp8 B fragments for MX K=128:
    // row n = g*256 + w*32 + nt*16 + l15 ; bytes k = half*128 + lq*32 + e
    i32x8 bfrag[4][2][2];
    const unsigned long long* wbp = w8 + (size_t)dir * 32768;
#pragma unroll
    for (int g = 0; g < 4; ++g)
#pragma unroll
        for (int nt = 0; nt < 2; ++nt) {
            int row = g * 256 + w * 32 + nt * 16 + l15;
#pragma unroll
            for (int half = 0; half < 2; ++half) {
                union { unsigned long long u[4]; i32x8 v; } t;
#pragma unroll
                for (int q = 0; q < 4; ++q)
                    t.u[q] = wbp[row * 32 + half * 16 + lq * 4 + q];
                bfrag[g][nt][half] = t.v;
            }
        }

    // Per-thread h ownership (update phase): b-local = l>>5, j = w*32 + (l&31)
    const int bl = l >> 5;
    const int jl = l & 31;
    const int j  = w * 32 + jl;
    const int bg = bbase + bl;           // batch within dir
    float cst = 0.0f;
    const int sc1 = 0x7F7F7F7F;          // e8m0 scales, all 1.0

    // xg prefetch (4 gates for this thread's (bg, j))
    unsigned short xq[4];
    {
        int t0 = dir ? (T_ - 1) : 0;
        const unsigned short* xp = xg + ((size_t)bg * T_ + t0) * NG + dir * 1024 + j;
#pragma unroll
        for (int g = 0; g < 4; ++g) xq[g] = xp[g * 256];
    }
    __syncthreads();   // hbuf zeros visible

    for (int s = 0; s < T_; ++s) {
        const int t = dir ? (T_ - 1 - s) : s;

        // A fragments: h(s-1) fp8 from LDS, m = l15, k = half*128 + lq*32 + e
        i32x8 af0, af1;
        {
            union { unsigned long long u[4]; i32x8 v; } t0, t1;
#pragma unroll
            for (int q = 0; q < 4; ++q) {
                t0.u[q] = hbuf[l15 * 33 + lq * 4 + q];
                t1.u[q] = hbuf[l15 * 33 + 16 + lq * 4 + q];
            }
            af0 = t0.v; af1 = t1.v;
        }

        // MX MFMA: 16 per wave (4 gates x 2 n-tiles x 2 K-halves)
        f32x4 acc[4][2];
#pragma unroll
        for (int g = 0; g < 4; ++g)
#pragma unroll
            for (int nt = 0; nt < 2; ++nt)
                acc[g][nt] = (f32x4){0.f, 0.f, 0.f, 0.f};
#pragma unroll
        for (int g = 0; g < 4; ++g)
#pragma unroll
            for (int nt = 0; nt < 2; ++nt) {
                acc[g][nt] = __builtin_amdgcn_mfma_scale_f32_16x16x128_f8f6f4(
                    af0, bfrag[g][nt][0], acc[g][nt], 0, 0, 0, sc1, 0, sc1);
                acc[g][nt] = __builtin_amdgcn_mfma_scale_f32_16x16x128_f8f6f4(
                    af1, bfrag[g][nt][1], acc[g][nt], 0, 0, 0, sc1, 0, sc1);
            }

        // Redistribute gates via wave-private LDS (C/D row = lq*4+r -> rows
        // 0,1 live in lanes lq==0). Per-wave DS ops are in-order.
        if (lq == 0) {
#pragma unroll
            for (int g = 0; g < 4; ++g)
#pragma unroll
                for (int nt = 0; nt < 2; ++nt) {
                    pg[w][g][0][nt * 16 + l15] = acc[g][nt][0];
                    pg[w][g][1][nt * 16 + l15] = acc[g][nt][1];
                }
        }
        float gi = pg[w][0][bl][jl] + bf2f(xq[0]);
        float gf = pg[w][1][bl][jl] + bf2f(xq[1]);
        float gg = pg[w][2][bl][jl] + bf2f(xq[2]);
        float go = pg[w][3][bl][jl] + bf2f(xq[3]);

        // prefetch next step's xg (latency hidden under update + barriers)
        {
            int sn = (s + 1 < T_) ? (s + 1) : s;
            int tn = dir ? (T_ - 1 - sn) : sn;
            const unsigned short* xp = xg + ((size_t)bg * T_ + tn) * NG + dir * 1024 + j;
#pragma unroll
            for (int g = 0; g < 4; ++g) xq[g] = xp[g * 256];
        }

        // cell update: exactly one h per lane
        float c = sigmf(gf) * cst + sigmf(gi) * tanh_fast(gg);
        cst = c;
        float h = sigmf(go) * tanh_fast(c);

        // global bf16 history store (async, no drain needed)
        h_hist[((size_t)(dir * 64 + bg) * T_ + t) * 256 + j] =
            (unsigned short)f2bf(h);

        bar_lds();   // all waves done reading hbuf (af) before overwrite
        unsigned int p8 = __builtin_amdgcn_cvt_pk_fp8_f32(h, h, 0, false);
        ((unsigned char*)hbuf)[bl * 264 + j] = (unsigned char)(p8 & 0xffu);
        bar_lds();   // hbuf writes visible before next step's af reads
    }
}

// ---------------------------------------------------------------------------
// Emissions (reads bf16 h history)
// ---------------------------------------------------------------------------
__global__ void __launch_bounds__(256) emis_k(
    const unsigned short* __restrict__ h_hist, const float* __restrict__ w_cls,
    const float* __restrict__ b_cls, float* __restrict__ em)
{
    int wid = threadIdx.x >> 6, lane = threadIdx.x & 63;
    size_t row = (size_t)blockIdx.x * 4 + wid;       // b*T + t
    const unsigned short* hf = h_hist + row * 256;
    const unsigned short* hb = h_hist + (size_t)64 * 512 * 256 + row * 256;
    ushort4 u0 = *(const ushort4*)(hf + 4 * lane);
    ushort4 u1 = *(const ushort4*)(hb + 4 * lane);
    float a0x = bf2f(u0.x), a0y = bf2f(u0.y), a0z = bf2f(u0.z), a0w = bf2f(u0.w);
    float a1x = bf2f(u1.x), a1y = bf2f(u1.y), a1z = bf2f(u1.z), a1w = bf2f(u1.w);
#pragma unroll
    for (int l = 0; l < L_; ++l) {
        const float* wr = w_cls + (size_t)l * 512;
        float4 w0 = *(const float4*)(wr + 4 * lane);
        float4 w1 = *(const float4*)(wr + 256 + 4 * lane);
        float d = a0x * w0.x + a0y * w0.y + a0z * w0.z + a0w * w0.w
                + a1x * w1.x + a1y * w1.y + a1z * w1.z + a1w * w1.w;
#pragma unroll
        for (int off = 32; off; off >>= 1) d += __shfl_down(d, off);
        if (lane == 0) em[row * L_ + l] = d + b_cls[l];
    }
}

// ---------------------------------------------------------------------------
// CRF NLL
// ---------------------------------------------------------------------------
__global__ void __launch_bounds__(64) crf_k(
    const float* __restrict__ em, const int* __restrict__ labels,
    const int* __restrict__ mask, const float* __restrict__ trans,
    const float* __restrict__ startv, const float* __restrict__ endv,
    float* __restrict__ out)
{
    int b = blockIdx.x, lane = threadIdx.x;
    const float* emb_ = em + (size_t)b * T_ * L_;
    const int* lab = labels + (size_t)b * T_;
    const int* msk = mask + (size_t)b * T_;
    __shared__ float alpha[L_];
    __shared__ float trs[81];
    for (int i = lane; i < 81; i += 64) trs[i] = trans[i];
    __syncthreads();

    float np = 0.0f;
    for (int t = 1 + lane; t < T_; t += 64)
        if (msk[t]) np += trs[lab[t - 1] * L_ + lab[t]] + emb_[(size_t)t * L_ + lab[t]];
    int mc = 0;
    for (int t = lane; t < T_; t += 64) mc += (msk[t] != 0);
#pragma unroll
    for (int off = 32; off; off >>= 1) {
        np += __shfl_down(np, off);
        mc += __shfl_down(mc, off);
    }
    float num = 0.0f;
    if (lane == 0) {
        int last = mc - 1;
        num = np + startv[lab[0]] + emb_[lab[0]] + endv[lab[last]];
    }

    if (lane < L_) alpha[lane] = startv[lane] + emb_[lane];
    __syncthreads();
    for (int t = 1; t < T_; ++t) {
        float na = 0.0f;
        if (lane < L_) {
            float m = -1e30f;
#pragma unroll
            for (int i = 0; i < L_; ++i) m = fmaxf(m, alpha[i] + trs[i * L_ + lane]);
            float s = 0.0f;
#pragma unroll
            for (int i = 0; i < L_; ++i) s += __expf(alpha[i] + trs[i * L_ + lane] - m);
            na = m + __logf(s) + emb_[(size_t)t * L_ + lane];
            if (!msk[t]) na = alpha[lane];
        }
        __syncthreads();
        if (lane < L_) alpha[lane] = na;
        __syncthreads();
    }
    float v = (lane < L_) ? alpha[lane] + endv[lane] : -1e30f;
    float m = v;
#pragma unroll
    for (int off = 32; off; off >>= 1) m = fmaxf(m, __shfl_xor(m, off));
    float s = (lane < L_) ? __expf(v - m) : 0.0f;
#pragma unroll
    for (int off = 32; off; off >>= 1) s += __shfl_xor(s, off);
    if (lane == 0) {
        float logZ = m + __logf(s);
        atomicAdd(out, (logZ - num) / (float)B_);
    }
}

__global__ void zero_out_k(float* out) { out[0] = 0.0f; }
__global__ void ws_fail_k(float* out, float v) { out[0] = v; }

// ---------------------------------------------------------------------------
extern "C" void kernel_launch(void* const* d_in, const int* in_sizes, int n_in,
                              void* d_out, int out_size, void* d_ws, size_t ws_size,
                              hipStream_t stream)
{
    const int*   ids    = (const int*)  d_in[0];
    const int*   amask  = (const int*)  d_in[1];
    const int*   labels = (const int*)  d_in[2];
    const float* emb    = (const float*)d_in[3];
    const float* w_ih_f = (const float*)d_in[4];
    const float* w_hh_f = (const float*)d_in[5];
    const float* b_ih_f = (const float*)d_in[6];
    const float* b_hh_f = (const float*)d_in[7];
    const float* w_ih_b = (const float*)d_in[8];
    const float* w_hh_b = (const float*)d_in[9];
    const float* b_ih_b = (const float*)d_in[10];
    const float* b_hh_b = (const float*)d_in[11];
    const float* w_cls  = (const float*)d_in[12];
    const float* b_cls  = (const float*)d_in[13];
    const float* trans  = (const float*)d_in[14];
    const float* startv = (const float*)d_in[15];
    const float* endv   = (const float*)d_in[16];
    float* out = (float*)d_out;

    // workspace layout
    size_t o_xg   = 0;                                   // bf16 xg: 128 MB
    size_t o_bias = o_xg + (size_t)NROW * NG * 2;
    size_t o_w8   = o_bias + 2048 * 4;                   // fp8 weights: 512 KB
    size_t o_hh   = o_w8 + (size_t)2 * 1024 * 256;       // h_hist: 32 MB
    size_t o_em   = o_hh + (size_t)2 * B_ * T_ * H_ * 2;
    size_t total  = o_em + (size_t)NROW * L_ * 4;

    if (ws_size < total) {
        ws_fail_k<<<1, 1, 0, stream>>>(out, -1.0e8f - (float)(ws_size >> 20));
        return;
    }

    unsigned short* xg       = (unsigned short*)((char*)d_ws + o_xg);
    float* bias              = (float*)((char*)d_ws + o_bias);
    unsigned int* w8         = (unsigned int*)((char*)d_ws + o_w8);
    unsigned short* h_hist   = (unsigned short*)((char*)d_ws + o_hh);
    float* em                = (float*)((char*)d_ws + o_em);

    bias_k<<<8, 256, 0, stream>>>(b_ih_f, b_hh_f, b_ih_b, b_hh_b, bias);
    prep_w8<<<512, 256, 0, stream>>>(w_hh_f, w_hh_b, w8);
    xg_gemm_mfma<<<dim3(NROW / 128, NG / 128), 256, 0, stream>>>(
        emb, ids, w_ih_f, w_ih_b, bias, xg);
    lstm_fused<<<64, 512, 0, stream>>>(xg, (const unsigned long long*)w8, h_hist);
    emis_k<<<NROW / 4, 256, 0, stream>>>(h_hist, w_cls, b_cls, em);
    zero_out_k<<<1, 1, 0, stream>>>(out);
    crf_k<<<B_, 64, 0, stream>>>(em, labels, amask, trans, startv, endv, out);
}